// Round 1
// baseline (16973.685 us; speedup 1.0000x reference)
//
#include <hip/hip_runtime.h>
#include <math.h>

namespace {

constexpr int B  = 4;
constexpr int S  = 1024;
constexpr int D  = 768;
constexpr int H  = 12;
constexpr int HD = 64;
constexpr int F  = 3072;
constexpr int L  = 4;
constexpr int M  = B * S;  // 4096 tokens

// ---------------- reductions (256-thread blocks, wave64) ----------------
__device__ __forceinline__ float wave_sum(float v) {
#pragma unroll
    for (int off = 32; off; off >>= 1) v += __shfl_xor(v, off, 64);
    return v;
}
__device__ __forceinline__ float wave_max(float v) {
#pragma unroll
    for (int off = 32; off; off >>= 1) v = fmaxf(v, __shfl_xor(v, off, 64));
    return v;
}
__device__ __forceinline__ float block_sum256(float v, float* sm) {
    v = wave_sum(v);
    __syncthreads();
    if ((threadIdx.x & 63) == 0) sm[threadIdx.x >> 6] = v;
    __syncthreads();
    return sm[0] + sm[1] + sm[2] + sm[3];
}
__device__ __forceinline__ float block_max256(float v, float* sm) {
    v = wave_max(v);
    __syncthreads();
    if ((threadIdx.x & 63) == 0) sm[threadIdx.x >> 6] = v;
    __syncthreads();
    return fmaxf(fmaxf(sm[0], sm[1]), fmaxf(sm[2], sm[3]));
}

// ---------------- embeddings + LayerNorm ----------------
// one block per token row; 768 = 3 * 256 elements per row
__global__ __launch_bounds__(256) void embed_ln_kernel(
    const int* __restrict__ x, const float* __restrict__ we,
    const float* __restrict__ pe, const float* __restrict__ te,
    const float* __restrict__ g, const float* __restrict__ bb,
    float* __restrict__ h) {
    __shared__ float sm[4];
    const int row = blockIdx.x;
    const int s = row & (S - 1);
    const int tok = x[row];
    const float* wrow = we + (size_t)tok * D;
    const float* prow = pe + (size_t)s * D;
    const int t = threadIdx.x;
    float v[3];
    float lsum = 0.f;
#pragma unroll
    for (int i = 0; i < 3; ++i) {
        int d = t + i * 256;
        v[i] = wrow[d] + prow[d] + te[d];
        lsum += v[i];
    }
    const float mu = block_sum256(lsum, sm) * (1.0f / D);
    float lvar = 0.f;
#pragma unroll
    for (int i = 0; i < 3; ++i) { float dv = v[i] - mu; lvar += dv * dv; }
    const float var = block_sum256(lvar, sm) * (1.0f / D);
    const float inv = rsqrtf(var + 1e-12f);
    float* hrow = h + (size_t)row * D;
#pragma unroll
    for (int i = 0; i < 3; ++i) {
        int d = t + i * 256;
        hrow[d] = (v[i] - mu) * inv * g[d] + bb[d];
    }
}

// ---------------- (optional residual) + LayerNorm ----------------
template <bool HAS_RES>
__global__ __launch_bounds__(256) void add_ln_kernel(
    const float* __restrict__ inp, const float* __restrict__ res,
    const float* __restrict__ g, const float* __restrict__ bb,
    float* __restrict__ out) {
    __shared__ float sm[4];
    const int row = blockIdx.x;
    const int t = threadIdx.x;
    const float* irow = inp + (size_t)row * D;
    const float* rrow = HAS_RES ? (res + (size_t)row * D) : nullptr;
    float v[3];
    float lsum = 0.f;
#pragma unroll
    for (int i = 0; i < 3; ++i) {
        int d = t + i * 256;
        v[i] = irow[d] + (HAS_RES ? rrow[d] : 0.0f);
        lsum += v[i];
    }
    const float mu = block_sum256(lsum, sm) * (1.0f / D);
    float lvar = 0.f;
#pragma unroll
    for (int i = 0; i < 3; ++i) { float dv = v[i] - mu; lvar += dv * dv; }
    const float var = block_sum256(lvar, sm) * (1.0f / D);
    const float inv = rsqrtf(var + 1e-12f);
    float* orow = out + (size_t)row * D;
#pragma unroll
    for (int i = 0; i < 3; ++i) {
        int d = t + i * 256;
        orow[d] = (v[i] - mu) * inv * g[d] + bb[d];
    }
}

// ---------------- fp32 tiled GEMM: C[M,N] = A[M,K] @ W[K,N] + bias ----------------
// BM=BN=64, BK=16, 256 threads, 4x4 micro-tile per thread.
// EPI: 0 = none, 1 = exact GELU
template <int EPI>
__global__ __launch_bounds__(256) void gemm_bias_kernel(
    const float* __restrict__ A, const float* __restrict__ W,
    const float* __restrict__ bias, float* __restrict__ C,
    int Mm, int N, int K) {
    constexpr int BM = 64, BN = 64, BK = 16;
    __shared__ float As[BK][BM + 1];  // +1 pad: transpose-write would be 16-way conflicted
    __shared__ float Bs[BK][BN];
    const int tid = threadIdx.x;
    const int tr = tid >> 4;          // 0..15
    const int tc = tid & 15;          // 0..15
    const int rowBase = blockIdx.y * BM;
    const int colBase = blockIdx.x * BN;
    float acc[4][4] = {};
    for (int k0 = 0; k0 < K; k0 += BK) {
#pragma unroll
        for (int r = 0; r < 4; ++r) {
            int idx = r * 256 + tid;
            int ar = idx >> 4, ac = idx & 15;
            As[ac][ar] = A[(size_t)(rowBase + ar) * K + k0 + ac];
        }
#pragma unroll
        for (int r = 0; r < 4; ++r) {
            int idx = r * 256 + tid;
            int br = idx >> 6, bc = idx & 63;
            Bs[br][bc] = W[(size_t)(k0 + br) * N + colBase + bc];
        }
        __syncthreads();
#pragma unroll
        for (int kk = 0; kk < BK; ++kk) {
            float a[4], bv[4];
#pragma unroll
            for (int i = 0; i < 4; ++i) a[i] = As[kk][tr * 4 + i];
#pragma unroll
            for (int j = 0; j < 4; ++j) bv[j] = Bs[kk][tc * 4 + j];
#pragma unroll
            for (int i = 0; i < 4; ++i)
#pragma unroll
                for (int j = 0; j < 4; ++j)
                    acc[i][j] = fmaf(a[i], bv[j], acc[i][j]);
        }
        __syncthreads();
    }
#pragma unroll
    for (int i = 0; i < 4; ++i) {
        int row = rowBase + tr * 4 + i;
#pragma unroll
        for (int j = 0; j < 4; ++j) {
            int col = colBase + tc * 4 + j;
            float c = acc[i][j] + bias[col];
            if (EPI == 1) c = 0.5f * c * (1.0f + erff(c * 0.70710678118654752f));
            C[(size_t)row * N + col] = c;
        }
    }
}

// ---------------- attention: one block per (b, h, q) ----------------
// q,k,v,o are (B,S,D) with head h occupying columns [h*HD, (h+1)*HD)
__global__ __launch_bounds__(256) void attention_kernel(
    const float* __restrict__ q, const float* __restrict__ k,
    const float* __restrict__ v, float* __restrict__ o) {
    __shared__ float qv[HD];
    __shared__ float sc[S];
    __shared__ float red[4];
    __shared__ float op[4][HD];
    const int qpos = blockIdx.x;
    const int bh = blockIdx.y;
    const int b = bh / H, hh = bh % H;
    const int t = threadIdx.x;
    const size_t headOff = (size_t)hh * HD;
    const float* qrow = q + ((size_t)(b * S + qpos) * D + headOff);
    if (t < HD) qv[t] = qrow[t];
    __syncthreads();

    float mysc[4];
    float lmax = -INFINITY;
#pragma unroll
    for (int c = 0; c < 4; ++c) {
        int kp = c * 256 + t;
        const float* krow = k + ((size_t)(b * S + kp) * D + headOff);
        float sdot = 0.f;
#pragma unroll
        for (int d = 0; d < HD; ++d) sdot = fmaf(qv[d], krow[d], sdot);
        sdot *= 0.125f;  // 1/sqrt(64)
        mysc[c] = sdot;
        lmax = fmaxf(lmax, sdot);
    }
    const float gmax = block_max256(lmax, red);
    float lsum = 0.f;
#pragma unroll
    for (int c = 0; c < 4; ++c) {
        float e = __expf(mysc[c] - gmax);
        sc[c * 256 + t] = e;
        lsum += e;
    }
    const float gsum = block_sum256(lsum, red);  // syncs -> sc[] visible
    const float inv = 1.0f / gsum;

    const int d = t & 63, c2 = t >> 6;
    const float* vbase = v + ((size_t)(b * S + c2 * 256) * D + headOff + d);
    float acc = 0.f;
    for (int kp = 0; kp < 256; ++kp) acc = fmaf(sc[c2 * 256 + kp], vbase[(size_t)kp * D], acc);
    op[c2][d] = acc;
    __syncthreads();
    if (t < HD) {
        float r = (op[0][t] + op[1][t] + op[2][t] + op[3][t]) * inv;
        o[(size_t)(b * S + qpos) * D + headOff + t] = r;
    }
}

// ---------------- pooler: out[b,d] = tanh(h[b,0,:] @ Wp + bp) ----------------
__global__ __launch_bounds__(768) void pooler_kernel(
    const float* __restrict__ h, const float* __restrict__ Wp,
    const float* __restrict__ bp, float* __restrict__ out) {
    const int b = blockIdx.x;
    const int d = threadIdx.x;  // 0..767
    const float* hrow = h + (size_t)b * S * D;
    float acc = bp[d];
    for (int kk = 0; kk < D; ++kk) acc = fmaf(hrow[kk], Wp[(size_t)kk * D + d], acc);
    out[(size_t)b * D + d] = tanhf(acc);
}

}  // namespace

extern "C" void kernel_launch(void* const* d_in, const int* in_sizes, int n_in,
                              void* d_out, int out_size, void* d_ws, size_t ws_size,
                              hipStream_t stream) {
    (void)in_sizes; (void)n_in; (void)out_size; (void)ws_size;

    const int*   x     = (const int*)  d_in[0];
    const float* we    = (const float*)d_in[1];
    const float* pe    = (const float*)d_in[2];
    const float* te    = (const float*)d_in[3];
    const float* emb_g = (const float*)d_in[4];
    const float* emb_b = (const float*)d_in[5];
    const float* Wq    = (const float*)d_in[6];
    const float* bq    = (const float*)d_in[7];
    const float* Wk    = (const float*)d_in[8];
    const float* bk    = (const float*)d_in[9];
    const float* Wv    = (const float*)d_in[10];
    const float* bv    = (const float*)d_in[11];
    const float* Wo    = (const float*)d_in[12];
    const float* bo    = (const float*)d_in[13];
    const float* ln1_g = (const float*)d_in[14];
    const float* ln1_b = (const float*)d_in[15];
    const float* W1    = (const float*)d_in[16];
    const float* b1    = (const float*)d_in[17];
    const float* W2    = (const float*)d_in[18];
    const float* b2    = (const float*)d_in[19];
    const float* ln2_g = (const float*)d_in[20];
    const float* ln2_b = (const float*)d_in[21];
    const float* Wp    = (const float*)d_in[22];
    const float* bp    = (const float*)d_in[23];

    float* ws = (float*)d_ws;
    float* h    = ws;                 // M*D
    float* qb   = h    + (size_t)M * D;
    float* kb   = qb   + (size_t)M * D;
    float* vb   = kb   + (size_t)M * D;
    float* ob   = vb   + (size_t)M * D;   // attention out / ffn2 out
    float* tb   = ob   + (size_t)M * D;   // M*F scratch (proj out / inter)

    embed_ln_kernel<<<M, 256, 0, stream>>>(x, we, pe, te, emb_g, emb_b, h);

    const dim3 gD(D / 64, M / 64);   // N=768 gemms
    const dim3 gF(F / 64, M / 64);   // N=3072 gemm

    for (int l = 0; l < L; ++l) {
        const float* Wq_l = Wq + (size_t)l * D * D;
        const float* Wk_l = Wk + (size_t)l * D * D;
        const float* Wv_l = Wv + (size_t)l * D * D;
        const float* Wo_l = Wo + (size_t)l * D * D;
        const float* W1_l = W1 + (size_t)l * D * F;
        const float* W2_l = W2 + (size_t)l * F * D;

        gemm_bias_kernel<0><<<gD, 256, 0, stream>>>(h, Wq_l, bq + l * D, qb, M, D, D);
        gemm_bias_kernel<0><<<gD, 256, 0, stream>>>(h, Wk_l, bk + l * D, kb, M, D, D);
        gemm_bias_kernel<0><<<gD, 256, 0, stream>>>(h, Wv_l, bv + l * D, vb, M, D, D);

        attention_kernel<<<dim3(S, B * H), 256, 0, stream>>>(qb, kb, vb, ob);

        gemm_bias_kernel<0><<<gD, 256, 0, stream>>>(ob, Wo_l, bo + l * D, tb, M, D, D);
        add_ln_kernel<true><<<M, 256, 0, stream>>>(tb, h, ln1_g + l * D, ln1_b + l * D, h);

        gemm_bias_kernel<1><<<gF, 256, 0, stream>>>(h, W1_l, b1 + l * F, tb, M, F, D);
        gemm_bias_kernel<1><<<gD, 256, 0, stream>>>(tb, W2_l, b2 + l * D, ob, M, D, F);
        add_ln_kernel<false><<<M, 256, 0, stream>>>(ob, nullptr, ln2_g + l * D, ln2_b + l * D, h);
    }

    pooler_kernel<<<B, D, 0, stream>>>(h, Wp, bp, (float*)d_out);
}

// Round 2
// 5383.111 us; speedup vs baseline: 3.1531x; 3.1531x over previous
//
#include <hip/hip_runtime.h>
#include <math.h>

namespace {

constexpr int B  = 4;
constexpr int S  = 1024;
constexpr int D  = 768;
constexpr int H  = 12;
constexpr int HD = 64;
constexpr int F  = 3072;
constexpr int L  = 4;
constexpr int M  = B * S;  // 4096 tokens

// ---------------- reductions (256-thread blocks, wave64) ----------------
__device__ __forceinline__ float wave_sum(float v) {
#pragma unroll
    for (int off = 32; off; off >>= 1) v += __shfl_xor(v, off, 64);
    return v;
}
__device__ __forceinline__ float block_sum256(float v, float* sm) {
    v = wave_sum(v);
    __syncthreads();
    if ((threadIdx.x & 63) == 0) sm[threadIdx.x >> 6] = v;
    __syncthreads();
    return sm[0] + sm[1] + sm[2] + sm[3];
}

// ---------------- embeddings + LayerNorm ----------------
__global__ __launch_bounds__(256) void embed_ln_kernel(
    const int* __restrict__ x, const float* __restrict__ we,
    const float* __restrict__ pe, const float* __restrict__ te,
    const float* __restrict__ g, const float* __restrict__ bb,
    float* __restrict__ h) {
    __shared__ float sm[4];
    const int row = blockIdx.x;
    const int s = row & (S - 1);
    const int tok = x[row];
    const float* wrow = we + (size_t)tok * D;
    const float* prow = pe + (size_t)s * D;
    const int t = threadIdx.x;
    float v[3];
    float lsum = 0.f;
#pragma unroll
    for (int i = 0; i < 3; ++i) {
        int d = t + i * 256;
        v[i] = wrow[d] + prow[d] + te[d];
        lsum += v[i];
    }
    const float mu = block_sum256(lsum, sm) * (1.0f / D);
    float lvar = 0.f;
#pragma unroll
    for (int i = 0; i < 3; ++i) { float dv = v[i] - mu; lvar += dv * dv; }
    const float var = block_sum256(lvar, sm) * (1.0f / D);
    const float inv = rsqrtf(var + 1e-12f);
    float* hrow = h + (size_t)row * D;
#pragma unroll
    for (int i = 0; i < 3; ++i) {
        int d = t + i * 256;
        hrow[d] = (v[i] - mu) * inv * g[d] + bb[d];
    }
}

// ---------------- (optional residual) + LayerNorm ----------------
template <bool HAS_RES>
__global__ __launch_bounds__(256) void add_ln_kernel(
    const float* __restrict__ inp, const float* __restrict__ res,
    const float* __restrict__ g, const float* __restrict__ bb,
    float* __restrict__ out) {
    __shared__ float sm[4];
    const int row = blockIdx.x;
    const int t = threadIdx.x;
    const float* irow = inp + (size_t)row * D;
    const float* rrow = HAS_RES ? (res + (size_t)row * D) : nullptr;
    float v[3];
    float lsum = 0.f;
#pragma unroll
    for (int i = 0; i < 3; ++i) {
        int d = t + i * 256;
        v[i] = irow[d] + (HAS_RES ? rrow[d] : 0.0f);
        lsum += v[i];
    }
    const float mu = block_sum256(lsum, sm) * (1.0f / D);
    float lvar = 0.f;
#pragma unroll
    for (int i = 0; i < 3; ++i) { float dv = v[i] - mu; lvar += dv * dv; }
    const float var = block_sum256(lvar, sm) * (1.0f / D);
    const float inv = rsqrtf(var + 1e-12f);
    float* orow = out + (size_t)row * D;
#pragma unroll
    for (int i = 0; i < 3; ++i) {
        int d = t + i * 256;
        orow[d] = (v[i] - mu) * inv * g[d] + bb[d];
    }
}

// ---------------- fp32 tiled GEMM: C[M,N] = A[M,K] @ W[K,N] + bias ----------------
template <int EPI>
__global__ __launch_bounds__(256) void gemm_bias_kernel(
    const float* __restrict__ A, const float* __restrict__ W,
    const float* __restrict__ bias, float* __restrict__ C,
    int Mm, int N, int K) {
    constexpr int BM = 64, BN = 64, BK = 16;
    __shared__ float As[BK][BM + 1];
    __shared__ float Bs[BK][BN];
    const int tid = threadIdx.x;
    const int tr = tid >> 4;
    const int tc = tid & 15;
    const int rowBase = blockIdx.y * BM;
    const int colBase = blockIdx.x * BN;
    float acc[4][4] = {};
    for (int k0 = 0; k0 < K; k0 += BK) {
#pragma unroll
        for (int r = 0; r < 4; ++r) {
            int idx = r * 256 + tid;
            int ar = idx >> 4, ac = idx & 15;
            As[ac][ar] = A[(size_t)(rowBase + ar) * K + k0 + ac];
        }
#pragma unroll
        for (int r = 0; r < 4; ++r) {
            int idx = r * 256 + tid;
            int br = idx >> 6, bc = idx & 63;
            Bs[br][bc] = W[(size_t)(k0 + br) * N + colBase + bc];
        }
        __syncthreads();
#pragma unroll
        for (int kk = 0; kk < BK; ++kk) {
            float a[4], bv[4];
#pragma unroll
            for (int i = 0; i < 4; ++i) a[i] = As[kk][tr * 4 + i];
#pragma unroll
            for (int j = 0; j < 4; ++j) bv[j] = Bs[kk][tc * 4 + j];
#pragma unroll
            for (int i = 0; i < 4; ++i)
#pragma unroll
                for (int j = 0; j < 4; ++j)
                    acc[i][j] = fmaf(a[i], bv[j], acc[i][j]);
        }
        __syncthreads();
    }
#pragma unroll
    for (int i = 0; i < 4; ++i) {
        int row = rowBase + tr * 4 + i;
#pragma unroll
        for (int j = 0; j < 4; ++j) {
            int col = colBase + tc * 4 + j;
            float c = acc[i][j] + bias[col];
            if (EPI == 1) c = 0.5f * c * (1.0f + erff(c * 0.70710678118654752f));
            C[(size_t)row * N + col] = c;
        }
    }
}

// ---------------- attention: one block per (b, h, 32-q-row tile) ----------------
// Flash-style: K/V tiles of 64 rows staged in LDS, online softmax in registers.
// Thread t: q-row qr = t>>3 for BOTH phases; phase A covers k = (t&7)*8..+7,
// phase B covers d = (t&7)*8..+7. Row stats (m,l,alpha) stay in-register.
__global__ __launch_bounds__(256) void attention_kernel(
    const float* __restrict__ q, const float* __restrict__ k,
    const float* __restrict__ v, float* __restrict__ o) {
    constexpr int QT = 32, KT = 64;
    __shared__ float Qs[QT][68];   // pad 68: float4-aligned rows, distinct banks per row
    __shared__ float Ks[KT][68];   // float4 cols swizzled by (row>>3): conflict-free QK reads
    __shared__ float Vs[KT][68];
    __shared__ float Ps[QT][68];

    const int t = threadIdx.x;
    const int qtile = blockIdx.x;       // 0..S/QT-1
    const int bh = blockIdx.y;          // 0..B*H-1
    const int b = bh / H, hh = bh % H;
    const size_t headOff = (size_t)hh * HD;
    const int qr = t >> 3;              // 0..31
    const int kslot = t & 7;            // 0..7
    const int dbase = kslot * 8;
    const int swz = kslot << 2;         // K swizzle term for this thread's k rows

    // stage Q tile (32x64) once, coalesced float4
    {
        const float* qbase = q + ((size_t)(b * S + qtile * QT) * D + headOff);
#pragma unroll
        for (int i = 0; i < 2; ++i) {
            int idx = i * 256 + t;
            int row = idx >> 4;
            int c4 = (idx & 15) * 4;
            *(float4*)&Qs[row][c4] = *(const float4*)(qbase + (size_t)row * D + c4);
        }
    }

    float m = -INFINITY, l = 0.f;
    float oacc[8] = {};

    for (int kt = 0; kt < S; kt += KT) {
        __syncthreads();  // prev iter's phase-B reads done before restaging
        const float* kbase = k + ((size_t)(b * S + kt) * D + headOff);
        const float* vbase = v + ((size_t)(b * S + kt) * D + headOff);
#pragma unroll
        for (int i = 0; i < 4; ++i) {
            int idx = i * 256 + t;
            int row = idx >> 4;
            int c4 = (idx & 15) * 4;
            float4 kv = *(const float4*)(kbase + (size_t)row * D + c4);
            float4 vv = *(const float4*)(vbase + (size_t)row * D + c4);
            *(float4*)&Ks[row][c4 ^ ((row >> 3) << 2)] = kv;
            *(float4*)&Vs[row][c4] = vv;
        }
        __syncthreads();

        // ---- phase A: scores for 8 k rows ----
        float s[8] = {};
#pragma unroll
        for (int d4 = 0; d4 < HD; d4 += 4) {
            const float4 q4 = *(const float4*)&Qs[qr][d4];
#pragma unroll
            for (int j = 0; j < 8; ++j) {
                const int row = dbase + j;  // kslot*8 + j; (row>>3)==kslot
                const float4 k4 = *(const float4*)&Ks[row][d4 ^ swz];
                s[j] = fmaf(q4.x, k4.x, s[j]);
                s[j] = fmaf(q4.y, k4.y, s[j]);
                s[j] = fmaf(q4.z, k4.z, s[j]);
                s[j] = fmaf(q4.w, k4.w, s[j]);
            }
        }
        float tm = -INFINITY;
#pragma unroll
        for (int j = 0; j < 8; ++j) { s[j] *= 0.125f; tm = fmaxf(tm, s[j]); }
        // row max across the 8 lanes owning this q row (consecutive lanes)
#pragma unroll
        for (int off = 1; off < 8; off <<= 1) tm = fmaxf(tm, __shfl_xor(tm, off, 64));
        const float mn = fmaxf(m, tm);
        const float alpha = __expf(m - mn);  // first tile: exp(-inf)=0
        float p[8];
        float ts = 0.f;
#pragma unroll
        for (int j = 0; j < 8; ++j) { p[j] = __expf(s[j] - mn); ts += p[j]; }
#pragma unroll
        for (int off = 1; off < 8; off <<= 1) ts += __shfl_xor(ts, off, 64);
        l = l * alpha + ts;
        m = mn;
        *(float4*)&Ps[qr][dbase]     = make_float4(p[0], p[1], p[2], p[3]);
        *(float4*)&Ps[qr][dbase + 4] = make_float4(p[4], p[5], p[6], p[7]);
#pragma unroll
        for (int j = 0; j < 8; ++j) oacc[j] *= alpha;
        __syncthreads();  // Ps visible

        // ---- phase B: oacc[dbase..dbase+7] += P[qr,:] @ V[:,d] ----
#pragma unroll
        for (int k4 = 0; k4 < KT; k4 += 4) {
            const float4 p4 = *(const float4*)&Ps[qr][k4];
            const float pv[4] = {p4.x, p4.y, p4.z, p4.w};
#pragma unroll
            for (int kk = 0; kk < 4; ++kk) {
                const float pk = pv[kk];
                const float4 v0 = *(const float4*)&Vs[k4 + kk][dbase];
                const float4 v1 = *(const float4*)&Vs[k4 + kk][dbase + 4];
                oacc[0] = fmaf(pk, v0.x, oacc[0]);
                oacc[1] = fmaf(pk, v0.y, oacc[1]);
                oacc[2] = fmaf(pk, v0.z, oacc[2]);
                oacc[3] = fmaf(pk, v0.w, oacc[3]);
                oacc[4] = fmaf(pk, v1.x, oacc[4]);
                oacc[5] = fmaf(pk, v1.y, oacc[5]);
                oacc[6] = fmaf(pk, v1.z, oacc[6]);
                oacc[7] = fmaf(pk, v1.w, oacc[7]);
            }
        }
    }

    const float invl = 1.0f / l;
    float* orow = o + ((size_t)(b * S + qtile * QT + qr) * D + headOff + dbase);
    *(float4*)orow       = make_float4(oacc[0] * invl, oacc[1] * invl, oacc[2] * invl, oacc[3] * invl);
    *(float4*)(orow + 4) = make_float4(oacc[4] * invl, oacc[5] * invl, oacc[6] * invl, oacc[7] * invl);
}

// ---------------- pooler ----------------
__global__ __launch_bounds__(768) void pooler_kernel(
    const float* __restrict__ h, const float* __restrict__ Wp,
    const float* __restrict__ bp, float* __restrict__ out) {
    const int b = blockIdx.x;
    const int d = threadIdx.x;
    const float* hrow = h + (size_t)b * S * D;
    float acc = bp[d];
    for (int kk = 0; kk < D; ++kk) acc = fmaf(hrow[kk], Wp[(size_t)kk * D + d], acc);
    out[(size_t)b * D + d] = tanhf(acc);
}

}  // namespace

extern "C" void kernel_launch(void* const* d_in, const int* in_sizes, int n_in,
                              void* d_out, int out_size, void* d_ws, size_t ws_size,
                              hipStream_t stream) {
    (void)in_sizes; (void)n_in; (void)out_size; (void)ws_size;

    const int*   x     = (const int*)  d_in[0];
    const float* we    = (const float*)d_in[1];
    const float* pe    = (const float*)d_in[2];
    const float* te    = (const float*)d_in[3];
    const float* emb_g = (const float*)d_in[4];
    const float* emb_b = (const float*)d_in[5];
    const float* Wq    = (const float*)d_in[6];
    const float* bq    = (const float*)d_in[7];
    const float* Wk    = (const float*)d_in[8];
    const float* bk    = (const float*)d_in[9];
    const float* Wv    = (const float*)d_in[10];
    const float* bv    = (const float*)d_in[11];
    const float* Wo    = (const float*)d_in[12];
    const float* bo    = (const float*)d_in[13];
    const float* ln1_g = (const float*)d_in[14];
    const float* ln1_b = (const float*)d_in[15];
    const float* W1    = (const float*)d_in[16];
    const float* b1    = (const float*)d_in[17];
    const float* W2    = (const float*)d_in[18];
    const float* b2    = (const float*)d_in[19];
    const float* ln2_g = (const float*)d_in[20];
    const float* ln2_b = (const float*)d_in[21];
    const float* Wp    = (const float*)d_in[22];
    const float* bp    = (const float*)d_in[23];

    float* ws = (float*)d_ws;
    float* h    = ws;                 // M*D
    float* qb   = h    + (size_t)M * D;
    float* kb   = qb   + (size_t)M * D;
    float* vb   = kb   + (size_t)M * D;
    float* ob   = vb   + (size_t)M * D;
    float* tb   = ob   + (size_t)M * D;   // M*F scratch

    embed_ln_kernel<<<M, 256, 0, stream>>>(x, we, pe, te, emb_g, emb_b, h);

    const dim3 gD(D / 64, M / 64);
    const dim3 gF(F / 64, M / 64);

    for (int l = 0; l < L; ++l) {
        const float* Wq_l = Wq + (size_t)l * D * D;
        const float* Wk_l = Wk + (size_t)l * D * D;
        const float* Wv_l = Wv + (size_t)l * D * D;
        const float* Wo_l = Wo + (size_t)l * D * D;
        const float* W1_l = W1 + (size_t)l * D * F;
        const float* W2_l = W2 + (size_t)l * F * D;

        gemm_bias_kernel<0><<<gD, 256, 0, stream>>>(h, Wq_l, bq + l * D, qb, M, D, D);
        gemm_bias_kernel<0><<<gD, 256, 0, stream>>>(h, Wk_l, bk + l * D, kb, M, D, D);
        gemm_bias_kernel<0><<<gD, 256, 0, stream>>>(h, Wv_l, bv + l * D, vb, M, D, D);

        attention_kernel<<<dim3(S / 32, B * H), 256, 0, stream>>>(qb, kb, vb, ob);

        gemm_bias_kernel<0><<<gD, 256, 0, stream>>>(ob, Wo_l, bo + l * D, tb, M, D, D);
        add_ln_kernel<true><<<M, 256, 0, stream>>>(tb, h, ln1_g + l * D, ln1_b + l * D, h);

        gemm_bias_kernel<1><<<gF, 256, 0, stream>>>(h, W1_l, b1 + l * F, tb, M, F, D);
        gemm_bias_kernel<1><<<gD, 256, 0, stream>>>(tb, W2_l, b2 + l * D, ob, M, D, F);
        add_ln_kernel<false><<<M, 256, 0, stream>>>(ob, nullptr, ln2_g + l * D, ln2_b + l * D, h);
    }

    pooler_kernel<<<B, D, 0, stream>>>(h, Wp, bp, (float*)d_out);
}

// Round 4
// 1727.175 us; speedup vs baseline: 9.8274x; 3.1167x over previous
//
#include <hip/hip_runtime.h>
#include <math.h>

namespace {

constexpr int B  = 4;
constexpr int S  = 1024;
constexpr int D  = 768;
constexpr int H  = 12;
constexpr int HD = 64;
constexpr int F  = 3072;
constexpr int L  = 4;
constexpr int M  = B * S;       // 4096 tokens
constexpr int NQKV = 3 * D;     // 2304

typedef __attribute__((ext_vector_type(4))) float  f32x4;
typedef __attribute__((ext_vector_type(8))) __bf16 bf16x8;
typedef __attribute__((ext_vector_type(8))) unsigned short u16x8;
typedef __attribute__((ext_vector_type(4))) unsigned short u16x4;

__device__ __forceinline__ float bf2f(unsigned short u) {
    return __uint_as_float((unsigned int)u << 16);
}
__device__ __forceinline__ unsigned short f2bf(float f) {
    unsigned int u = __float_as_uint(f);
    unsigned int r = u + 0x7fffu + ((u >> 16) & 1u);  // RNE (finite inputs)
    return (unsigned short)(r >> 16);
}

__device__ __forceinline__ void gload16(const void* gptr, void* ldsptr) {
    __builtin_amdgcn_global_load_lds(
        (const __attribute__((address_space(1))) unsigned int*)gptr,
        (__attribute__((address_space(3))) unsigned int*)ldsptr,
        16, 0, 0);
}

// ---------------- reductions ----------------
__device__ __forceinline__ float wave_sum(float v) {
#pragma unroll
    for (int off = 32; off; off >>= 1) v += __shfl_xor(v, off, 64);
    return v;
}
__device__ __forceinline__ float block_sum256(float v, float* sm) {
    v = wave_sum(v);
    __syncthreads();
    if ((threadIdx.x & 63) == 0) sm[threadIdx.x >> 6] = v;
    __syncthreads();
    return sm[0] + sm[1] + sm[2] + sm[3];
}

// ---------------- weight prep: transpose fp32 [R][C] -> bf16 [C][R] ----------------
__device__ __forceinline__ void transpose_tile(const float* __restrict__ src,
                                               unsigned short* __restrict__ dst,
                                               int R, int C) {
    __shared__ float tile[32][33];
    const int cb = blockIdx.x * 32, rb = blockIdx.y * 32;
    const int t = threadIdx.x;
    {
        const int r = t >> 3, cq = (t & 7) * 4;
        const float4 v = *(const float4*)&src[(size_t)(rb + r) * C + cb + cq];
        tile[r][cq + 0] = v.x; tile[r][cq + 1] = v.y;
        tile[r][cq + 2] = v.z; tile[r][cq + 3] = v.w;
    }
    __syncthreads();
    {
        const int dc = t >> 3, rq = (t & 7) * 4;
        u16x4 o;
#pragma unroll
        for (int j = 0; j < 4; ++j) o[j] = f2bf(tile[rq + j][dc]);
        *(u16x4*)&dst[(size_t)(cb + dc) * R + rb + rq] = o;
    }
}

__global__ __launch_bounds__(256) void transpose_qkvo_kernel(
    const float* __restrict__ Wq, const float* __restrict__ Wk,
    const float* __restrict__ Wv, const float* __restrict__ Wo,
    unsigned short* __restrict__ Wqkv_t, unsigned short* __restrict__ Wo_t) {
    const int z = blockIdx.z;
    const int l = z >> 2, which = z & 3;
    const float* src = (which == 0 ? Wq : which == 1 ? Wk : which == 2 ? Wv : Wo)
                       + (size_t)l * D * D;
    unsigned short* dst = (which < 3)
        ? Wqkv_t + ((size_t)l * NQKV + which * D) * D
        : Wo_t + (size_t)l * D * D;
    transpose_tile(src, dst, D, D);
}

__global__ __launch_bounds__(256) void transpose_w_kernel(
    const float* __restrict__ src0, unsigned short* __restrict__ dst0, int R, int C) {
    const int l = blockIdx.z;
    transpose_tile(src0 + (size_t)l * R * C, dst0 + (size_t)l * R * C, R, C);
}

__global__ __launch_bounds__(256) void bias_concat_kernel(
    const float* __restrict__ bq, const float* __restrict__ bk,
    const float* __restrict__ bv, float* __restrict__ bqkv) {
    const int i = blockIdx.x * 256 + threadIdx.x;
    if (i >= L * NQKV) return;
    const int l = i / NQKV, j = i % NQKV;
    float v = (j < D) ? bq[l * D + j] : (j < 2 * D) ? bk[l * D + j - D] : bv[l * D + j - 2 * D];
    bqkv[i] = v;
}

// ---------------- embeddings + LayerNorm -> fp32 stream + bf16 copy ----------------
__global__ __launch_bounds__(256) void embed_ln_kernel(
    const int* __restrict__ x, const float* __restrict__ we,
    const float* __restrict__ pe, const float* __restrict__ te,
    const float* __restrict__ g, const float* __restrict__ bb,
    float* __restrict__ hres, unsigned short* __restrict__ hbf) {
    __shared__ float sm[4];
    const int row = blockIdx.x;
    const int s = row & (S - 1);
    const int tok = x[row];
    const int t = threadIdx.x;
    const bool act = t < 192;
    const int d = t * 4;
    float v[4] = {};
    if (act) {
        const float4 w = *(const float4*)&we[(size_t)tok * D + d];
        const float4 p = *(const float4*)&pe[(size_t)s * D + d];
        const float4 tt = *(const float4*)&te[d];
        v[0] = w.x + p.x + tt.x; v[1] = w.y + p.y + tt.y;
        v[2] = w.z + p.z + tt.z; v[3] = w.w + p.w + tt.w;
    }
    const float mu = block_sum256(v[0] + v[1] + v[2] + v[3], sm) * (1.0f / D);
    float lvar = 0.f;
    if (act) {
#pragma unroll
        for (int i = 0; i < 4; ++i) { float dv = v[i] - mu; lvar += dv * dv; }
    }
    const float var = block_sum256(lvar, sm) * (1.0f / D);
    const float inv = rsqrtf(var + 1e-12f);
    if (act) {
        const float4 g4 = *(const float4*)&g[d];
        const float4 b4 = *(const float4*)&bb[d];
        float o[4];
        o[0] = (v[0] - mu) * inv * g4.x + b4.x;
        o[1] = (v[1] - mu) * inv * g4.y + b4.y;
        o[2] = (v[2] - mu) * inv * g4.z + b4.z;
        o[3] = (v[3] - mu) * inv * g4.w + b4.w;
        *(float4*)&hres[(size_t)row * D + d] = make_float4(o[0], o[1], o[2], o[3]);
        u16x4 ob;
#pragma unroll
        for (int i = 0; i < 4; ++i) ob[i] = f2bf(o[i]);
        *(u16x4*)&hbf[(size_t)row * D + d] = ob;
    }
}

// ---------------- (optional residual) + LayerNorm, fp32 in -> fp32 stream + bf16 copy ----------------
// safe when inp == outres or res == outres (row-local, regs loaded before write)
template <bool HAS_RES>
__global__ __launch_bounds__(256) void add_ln_kernel(
    const float* __restrict__ inp, const float* __restrict__ res,
    const float* __restrict__ g, const float* __restrict__ bb,
    float* __restrict__ outres, unsigned short* __restrict__ outbf) {
    __shared__ float sm[4];
    const int row = blockIdx.x;
    const int t = threadIdx.x;
    const bool act = t < 192;
    const int d = t * 4;
    float v[4] = {};
    if (act) {
        const float4 iv = *(const float4*)&inp[(size_t)row * D + d];
        v[0] = iv.x; v[1] = iv.y; v[2] = iv.z; v[3] = iv.w;
        if (HAS_RES) {
            const float4 rv = *(const float4*)&res[(size_t)row * D + d];
            v[0] += rv.x; v[1] += rv.y; v[2] += rv.z; v[3] += rv.w;
        }
    }
    const float mu = block_sum256(v[0] + v[1] + v[2] + v[3], sm) * (1.0f / D);
    float lvar = 0.f;
    if (act) {
#pragma unroll
        for (int i = 0; i < 4; ++i) { float dv = v[i] - mu; lvar += dv * dv; }
    }
    const float var = block_sum256(lvar, sm) * (1.0f / D);
    const float inv = rsqrtf(var + 1e-12f);
    if (act) {
        const float4 g4 = *(const float4*)&g[d];
        const float4 b4 = *(const float4*)&bb[d];
        float o[4];
        o[0] = (v[0] - mu) * inv * g4.x + b4.x;
        o[1] = (v[1] - mu) * inv * g4.y + b4.y;
        o[2] = (v[2] - mu) * inv * g4.z + b4.z;
        o[3] = (v[3] - mu) * inv * g4.w + b4.w;
        *(float4*)&outres[(size_t)row * D + d] = make_float4(o[0], o[1], o[2], o[3]);
        u16x4 ob;
#pragma unroll
        for (int i = 0; i < 4; ++i) ob[i] = f2bf(o[i]);
        *(u16x4*)&outbf[(size_t)row * D + d] = ob;
    }
}

// ---------------- bf16 MFMA GEMM: C[M,N] = A[M,K] @ Bw[N,K]^T + bias ----------------
// CT = float (fp32 out) or unsigned short (bf16 out). EPI: 0 none, 1 exact GELU.
template <int EPI, typename CT>
__global__ __launch_bounds__(256) void gemm_mfma_kernel(
    const unsigned short* __restrict__ A,    // [M][K] bf16
    const unsigned short* __restrict__ Bw,   // [N][K] bf16 (pre-transposed weights)
    const float* __restrict__ bias,          // [N] fp32
    CT* __restrict__ C,                      // [M][N]
    int N, int K) {
    constexpr int BK = 32;
    __shared__ unsigned short Asl[2][128 * BK];
    __shared__ unsigned short Bsl[2][128 * BK];

    const int t = threadIdx.x;
    const int lane = t & 63;
    const int wid = t >> 6;
    const int lr = lane & 15;
    const int kh = lane >> 4;
    const int wrBase = (wid >> 1) * 64;
    const int wcBase = (wid & 1) * 64;
    const int rowBase = blockIdx.y * 128;
    const int colBase = blockIdx.x * 128;

    f32x4 acc[4][4] = {};

    const int s_lo = t;
    const int r0 = s_lo >> 2, c0 = (s_lo & 3) ^ ((r0 >> 1) & 3);
    const int s_hi = 256 + t;
    const int r1 = s_hi >> 2, c1 = (s_hi & 3) ^ ((r1 >> 1) & 3);
    const unsigned ldsOff0 = (unsigned)((t & 192) * 8);
    const unsigned ldsOff1 = (unsigned)((256 + (t & 192)) * 8);

#define STAGE(p, k0)                                                              \
    do {                                                                          \
        gload16(A + (size_t)(rowBase + r0) * K + (k0) + c0 * 8, &Asl[p][ldsOff0]);\
        gload16(A + (size_t)(rowBase + r1) * K + (k0) + c1 * 8, &Asl[p][ldsOff1]);\
        gload16(Bw + (size_t)(colBase + r0) * K + (k0) + c0 * 8, &Bsl[p][ldsOff0]);\
        gload16(Bw + (size_t)(colBase + r1) * K + (k0) + c1 * 8, &Bsl[p][ldsOff1]);\
    } while (0)

    STAGE(0, 0);
    __syncthreads();

    const int nt = K / BK;
    for (int tt = 0; tt < nt; ++tt) {
        const int p = tt & 1;
        if (tt + 1 < nt) STAGE(p ^ 1, (tt + 1) * BK);

        bf16x8 af[4], bfr[4];
#pragma unroll
        for (int mi = 0; mi < 4; ++mi) {
            const int ar = wrBase + mi * 16 + lr;
            const int ch = kh ^ ((ar >> 1) & 3);
            af[mi] = *(const bf16x8*)&Asl[p][ar * BK + ch * 8];
        }
#pragma unroll
        for (int nj = 0; nj < 4; ++nj) {
            const int bc = wcBase + nj * 16 + lr;
            const int ch = kh ^ ((bc >> 1) & 3);
            bfr[nj] = *(const bf16x8*)&Bsl[p][bc * BK + ch * 8];
        }
#pragma unroll
        for (int mi = 0; mi < 4; ++mi)
#pragma unroll
            for (int nj = 0; nj < 4; ++nj)
                acc[mi][nj] = __builtin_amdgcn_mfma_f32_16x16x32_bf16(
                    af[mi], bfr[nj], acc[mi][nj], 0, 0, 0);
        __syncthreads();
    }
#undef STAGE

#pragma unroll
    for (int nj = 0; nj < 4; ++nj) {
        const int col = colBase + wcBase + nj * 16 + lr;
        const float bc = bias[col];
#pragma unroll
        for (int mi = 0; mi < 4; ++mi) {
            const int row = rowBase + wrBase + mi * 16 + kh * 4;
#pragma unroll
            for (int j = 0; j < 4; ++j) {
                float v = acc[mi][nj][j] + bc;
                if (EPI == 1) v = 0.5f * v * (1.0f + erff(v * 0.70710678118654752f));
                if constexpr (sizeof(CT) == 4) {
                    C[(size_t)(row + j) * N + col] = v;
                } else {
                    C[(size_t)(row + j) * N + col] = f2bf(v);
                }
            }
        }
    }
}

// ---------------- flash attention: fp32 qkv in, bf16 out ----------------
// qkv: [M][2304] fp32 (q|k|v). One block per (b, h, 32-q-row tile).
__global__ __launch_bounds__(256) void attention_kernel(
    const float* __restrict__ qkv, unsigned short* __restrict__ o) {
    constexpr int QT = 32, KT = 64, QSTR = NQKV;
    __shared__ float Qs[QT][68];
    __shared__ float Ks[KT][68];   // float4 cols swizzled by (row>>3)
    __shared__ float Vs[KT][68];
    __shared__ float Ps[QT][68];

    const int t = threadIdx.x;
    const int qtile = blockIdx.x;
    const int bh = blockIdx.y;
    const int b = bh / H, hh = bh % H;
    const int headOff = hh * HD;
    const int qr = t >> 3;
    const int kslot = t & 7;
    const int dbase = kslot * 8;
    const int swz = kslot << 2;

    {   // stage Q tile (32x64) coalesced float4
        const float* qbase = qkv + ((size_t)(b * S + qtile * QT) * QSTR + headOff);
#pragma unroll
        for (int i = 0; i < 2; ++i) {
            int idx = i * 256 + t;
            int row = idx >> 4;
            int c4 = (idx & 15) * 4;
            *(float4*)&Qs[row][c4] = *(const float4*)(qbase + (size_t)row * QSTR + c4);
        }
    }

    float m = -INFINITY, l = 0.f;
    float oacc[8] = {};

    for (int kt = 0; kt < S; kt += KT) {
        __syncthreads();
        const float* kbase = qkv + ((size_t)(b * S + kt) * QSTR + D + headOff);
        const float* vbase = qkv + ((size_t)(b * S + kt) * QSTR + 2 * D + headOff);
#pragma unroll
        for (int i = 0; i < 4; ++i) {
            int idx = i * 256 + t;
            int row = idx >> 4;
            int c4 = (idx & 15) * 4;
            float4 kv = *(const float4*)(kbase + (size_t)row * QSTR + c4);
            float4 vv = *(const float4*)(vbase + (size_t)row * QSTR + c4);
            *(float4*)&Ks[row][c4 ^ ((row >> 3) << 2)] = kv;
            *(float4*)&Vs[row][c4] = vv;
        }
        __syncthreads();

        // phase A: scores for 8 k rows
        float s[8] = {};
#pragma unroll
        for (int d4 = 0; d4 < HD; d4 += 4) {
            const float4 q4 = *(const float4*)&Qs[qr][d4];
#pragma unroll
            for (int j = 0; j < 8; ++j) {
                const float4 k4 = *(const float4*)&Ks[dbase + j][d4 ^ swz];
                s[j] = fmaf(q4.x, k4.x, s[j]);
                s[j] = fmaf(q4.y, k4.y, s[j]);
                s[j] = fmaf(q4.z, k4.z, s[j]);
                s[j] = fmaf(q4.w, k4.w, s[j]);
            }
        }
        float tm = -INFINITY;
#pragma unroll
        for (int j = 0; j < 8; ++j) { s[j] *= 0.125f; tm = fmaxf(tm, s[j]); }
#pragma unroll
        for (int off = 1; off < 8; off <<= 1) tm = fmaxf(tm, __shfl_xor(tm, off, 64));
        const float mn = fmaxf(m, tm);
        const float alpha = __expf(m - mn);
        float p[8];
        float ts = 0.f;
#pragma unroll
        for (int j = 0; j < 8; ++j) { p[j] = __expf(s[j] - mn); ts += p[j]; }
#pragma unroll
        for (int off = 1; off < 8; off <<= 1) ts += __shfl_xor(ts, off, 64);
        l = l * alpha + ts;
        m = mn;
        *(float4*)&Ps[qr][dbase]     = make_float4(p[0], p[1], p[2], p[3]);
        *(float4*)&Ps[qr][dbase + 4] = make_float4(p[4], p[5], p[6], p[7]);
#pragma unroll
        for (int j = 0; j < 8; ++j) oacc[j] *= alpha;
        __syncthreads();

        // phase B
#pragma unroll
        for (int k4 = 0; k4 < KT; k4 += 4) {
            const float4 p4 = *(const float4*)&Ps[qr][k4];
            const float pv[4] = {p4.x, p4.y, p4.z, p4.w};
#pragma unroll
            for (int kk = 0; kk < 4; ++kk) {
                const float pk = pv[kk];
                const float4 v0 = *(const float4*)&Vs[k4 + kk][dbase];
                const float4 v1 = *(const float4*)&Vs[k4 + kk][dbase + 4];
                oacc[0] = fmaf(pk, v0.x, oacc[0]);
                oacc[1] = fmaf(pk, v0.y, oacc[1]);
                oacc[2] = fmaf(pk, v0.z, oacc[2]);
                oacc[3] = fmaf(pk, v0.w, oacc[3]);
                oacc[4] = fmaf(pk, v1.x, oacc[4]);
                oacc[5] = fmaf(pk, v1.y, oacc[5]);
                oacc[6] = fmaf(pk, v1.z, oacc[6]);
                oacc[7] = fmaf(pk, v1.w, oacc[7]);
            }
        }
    }

    const float invl = 1.0f / l;
    u16x8 ou;
#pragma unroll
    for (int j = 0; j < 8; ++j) ou[j] = f2bf(oacc[j] * invl);
    *(u16x8*)(o + (size_t)(b * S + qtile * QT + qr) * D + headOff + dbase) = ou;
}

// ---------------- pooler (fp32 h) ----------------
__global__ __launch_bounds__(768) void pooler_kernel(
    const float* __restrict__ h, const float* __restrict__ Wp,
    const float* __restrict__ bp, float* __restrict__ out) {
    const int b = blockIdx.x;
    const int d = threadIdx.x;
    const float* hrow = h + (size_t)b * S * D;
    float acc = bp[d];
    for (int kk = 0; kk < D; ++kk) acc = fmaf(hrow[kk], Wp[(size_t)kk * D + d], acc);
    out[(size_t)b * D + d] = tanhf(acc);
}

}  // namespace

extern "C" void kernel_launch(void* const* d_in, const int* in_sizes, int n_in,
                              void* d_out, int out_size, void* d_ws, size_t ws_size,
                              hipStream_t stream) {
    (void)in_sizes; (void)n_in; (void)out_size; (void)ws_size;

    const int*   x     = (const int*)  d_in[0];
    const float* we    = (const float*)d_in[1];
    const float* pe    = (const float*)d_in[2];
    const float* te    = (const float*)d_in[3];
    const float* emb_g = (const float*)d_in[4];
    const float* emb_b = (const float*)d_in[5];
    const float* Wq    = (const float*)d_in[6];
    const float* bq    = (const float*)d_in[7];
    const float* Wk    = (const float*)d_in[8];
    const float* bk    = (const float*)d_in[9];
    const float* Wv    = (const float*)d_in[10];
    const float* bv    = (const float*)d_in[11];
    const float* Wo    = (const float*)d_in[12];
    const float* bo    = (const float*)d_in[13];
    const float* ln1_g = (const float*)d_in[14];
    const float* ln1_b = (const float*)d_in[15];
    const float* W1    = (const float*)d_in[16];
    const float* b1    = (const float*)d_in[17];
    const float* W2    = (const float*)d_in[18];
    const float* b2    = (const float*)d_in[19];
    const float* ln2_g = (const float*)d_in[20];
    const float* ln2_b = (const float*)d_in[21];
    const float* Wp    = (const float*)d_in[22];
    const float* bp    = (const float*)d_in[23];

    // workspace layout (~113 MB):
    //   h_res  : M*D fp32   — residual/stream (12.58 MB)
    //   h_bf   : M*D bf16   — GEMM-A staging copy; also attention output (6.29 MB)
    //   big    : M*NQKV fp32 (37.75 MB) — qkv fp32; then oproj fp32 (base);
    //            then inter bf16 (base, 25.17 MB)
    //   weights: bf16 transposed (56.62 MB) + bqkv fp32
    char* wp8 = (char*)d_ws;
    float*          h_res  = (float*)wp8;                         wp8 += (size_t)M * D * 4;
    unsigned short* h_bf   = (unsigned short*)wp8;                wp8 += (size_t)M * D * 2;
    float*          big    = (float*)wp8;                         wp8 += (size_t)M * NQKV * 4;
    float*          qkv_f  = big;
    float*          oproj  = big;
    unsigned short* inter  = (unsigned short*)big;
    unsigned short* attno  = h_bf;
    float*          ffn2o  = h_res;   // GEMM2 writes stream in place (old h_res dead)
    unsigned short* Wqkv_t = (unsigned short*)wp8;                wp8 += (size_t)L * NQKV * D * 2;
    unsigned short* Wo_t   = (unsigned short*)wp8;                wp8 += (size_t)L * D * D * 2;
    unsigned short* W1_t   = (unsigned short*)wp8;                wp8 += (size_t)L * F * D * 2;
    unsigned short* W2_t   = (unsigned short*)wp8;                wp8 += (size_t)L * D * F * 2;
    float*          bqkv   = (float*)wp8;

    // ---- weight prep (bf16 transposed) ----
    transpose_qkvo_kernel<<<dim3(24, 24, 16), 256, 0, stream>>>(Wq, Wk, Wv, Wo, Wqkv_t, Wo_t);
    transpose_w_kernel<<<dim3(96, 24, 4), 256, 0, stream>>>(W1, W1_t, D, F);   // -> [F][D]
    transpose_w_kernel<<<dim3(24, 96, 4), 256, 0, stream>>>(W2, W2_t, F, D);   // -> [D][F]
    bias_concat_kernel<<<dim3((L * NQKV + 255) / 256), 256, 0, stream>>>(bq, bk, bv, bqkv);

    embed_ln_kernel<<<M, 256, 0, stream>>>(x, we, pe, te, emb_g, emb_b, h_res, h_bf);

    for (int l = 0; l < L; ++l) {
        // fused QKV -> fp32
        gemm_mfma_kernel<0, float><<<dim3(NQKV / 128, M / 128), 256, 0, stream>>>(
            h_bf, Wqkv_t + (size_t)l * NQKV * D, bqkv + l * NQKV, qkv_f, NQKV, D);

        attention_kernel<<<dim3(S / 32, B * H), 256, 0, stream>>>(qkv_f, attno);

        // O-proj -> fp32 (overwrites dead qkv region)
        gemm_mfma_kernel<0, float><<<dim3(D / 128, M / 128), 256, 0, stream>>>(
            attno, Wo_t + (size_t)l * D * D, bo + l * D, oproj, D, D);
        add_ln_kernel<true><<<M, 256, 0, stream>>>(
            oproj, h_res, ln1_g + l * D, ln1_b + l * D, h_res, h_bf);

        // FFN1 + GELU -> bf16 inter (overwrites dead oproj region)
        gemm_mfma_kernel<1, unsigned short><<<dim3(F / 128, M / 128), 256, 0, stream>>>(
            h_bf, W1_t + (size_t)l * F * D, b1 + l * F, inter, F, D);
        // FFN2 + GELU -> fp32, in place into the stream buffer
        gemm_mfma_kernel<1, float><<<dim3(D / 128, M / 128), 256, 0, stream>>>(
            inter, W2_t + (size_t)l * D * F, b2 + l * D, ffn2o, D, F);
        add_ln_kernel<false><<<M, 256, 0, stream>>>(
            ffn2o, nullptr, ln2_g + l * D, ln2_b + l * D, h_res, h_bf);
    }

    pooler_kernel<<<B, D, 0, stream>>>(h_res, Wp, bp, (float*)d_out);
}

// Round 5
// 953.814 us; speedup vs baseline: 17.7956x; 1.8108x over previous
//
#include <hip/hip_runtime.h>
#include <math.h>

namespace {

constexpr int B  = 4;
constexpr int S  = 1024;
constexpr int D  = 768;
constexpr int H  = 12;
constexpr int HD = 64;
constexpr int F  = 3072;
constexpr int L  = 4;
constexpr int M  = B * S;       // 4096 tokens
constexpr int NQKV = 3 * D;     // 2304
constexpr int NQK = 2 * D;      // 1536 (q|k packed)

typedef __attribute__((ext_vector_type(4))) float    f32x4;
typedef _Float16 f16x8 __attribute__((ext_vector_type(8)));
typedef __attribute__((ext_vector_type(8))) unsigned short u16x8;
typedef __attribute__((ext_vector_type(4))) unsigned short u16x4;

__device__ __forceinline__ unsigned short f2h_u(float f) {
    _Float16 h = (_Float16)f;
    return __builtin_bit_cast(unsigned short, h);
}

__device__ __forceinline__ void gload16(const void* gptr, void* ldsptr) {
    __builtin_amdgcn_global_load_lds(
        (const __attribute__((address_space(1))) unsigned int*)gptr,
        (__attribute__((address_space(3))) unsigned int*)ldsptr,
        16, 0, 0);
}

// ---------------- reductions ----------------
__device__ __forceinline__ float wave_sum(float v) {
#pragma unroll
    for (int off = 32; off; off >>= 1) v += __shfl_xor(v, off, 64);
    return v;
}
__device__ __forceinline__ float block_sum256(float v, float* sm) {
    v = wave_sum(v);
    __syncthreads();
    if ((threadIdx.x & 63) == 0) sm[threadIdx.x >> 6] = v;
    __syncthreads();
    return sm[0] + sm[1] + sm[2] + sm[3];
}

// ---------------- weight prep: transpose fp32 [R][C] -> fp16 [C][R] ----------------
__device__ __forceinline__ void transpose_tile(const float* __restrict__ src,
                                               unsigned short* __restrict__ dst,
                                               int R, int C) {
    __shared__ float tile[32][33];
    const int cb = blockIdx.x * 32, rb = blockIdx.y * 32;
    const int t = threadIdx.x;
    {
        const int r = t >> 3, cq = (t & 7) * 4;
        const float4 v = *(const float4*)&src[(size_t)(rb + r) * C + cb + cq];
        tile[r][cq + 0] = v.x; tile[r][cq + 1] = v.y;
        tile[r][cq + 2] = v.z; tile[r][cq + 3] = v.w;
    }
    __syncthreads();
    {
        const int dc = t >> 3, rq = (t & 7) * 4;
        u16x4 o;
#pragma unroll
        for (int j = 0; j < 4; ++j) o[j] = f2h_u(tile[rq + j][dc]);
        *(u16x4*)&dst[(size_t)(cb + dc) * R + rb + rq] = o;
    }
}

__global__ __launch_bounds__(256) void transpose_qkvo_kernel(
    const float* __restrict__ Wq, const float* __restrict__ Wk,
    const float* __restrict__ Wv, const float* __restrict__ Wo,
    unsigned short* __restrict__ Wqkv_t, unsigned short* __restrict__ Wo_t) {
    const int z = blockIdx.z;
    const int l = z >> 2, which = z & 3;
    const float* src = (which == 0 ? Wq : which == 1 ? Wk : which == 2 ? Wv : Wo)
                       + (size_t)l * D * D;
    unsigned short* dst = (which < 3)
        ? Wqkv_t + ((size_t)l * NQKV + which * D) * D
        : Wo_t + (size_t)l * D * D;
    transpose_tile(src, dst, D, D);
}

__global__ __launch_bounds__(256) void transpose_w_kernel(
    const float* __restrict__ src0, unsigned short* __restrict__ dst0, int R, int C) {
    const int l = blockIdx.z;
    transpose_tile(src0 + (size_t)l * R * C, dst0 + (size_t)l * R * C, R, C);
}

__global__ __launch_bounds__(256) void bias_concat_kernel(
    const float* __restrict__ bq, const float* __restrict__ bk,
    const float* __restrict__ bv, float* __restrict__ bqkv) {
    const int i = blockIdx.x * 256 + threadIdx.x;
    if (i >= L * NQKV) return;
    const int l = i / NQKV, j = i % NQKV;
    float v = (j < D) ? bq[l * D + j] : (j < 2 * D) ? bk[l * D + j - D] : bv[l * D + j - 2 * D];
    bqkv[i] = v;
}

// ---------------- embeddings + LayerNorm -> fp32 stream + fp16 copy ----------------
__global__ __launch_bounds__(256) void embed_ln_kernel(
    const int* __restrict__ x, const float* __restrict__ we,
    const float* __restrict__ pe, const float* __restrict__ te,
    const float* __restrict__ g, const float* __restrict__ bb,
    float* __restrict__ hres, unsigned short* __restrict__ hh) {
    __shared__ float sm[4];
    const int row = blockIdx.x;
    const int s = row & (S - 1);
    const int tok = x[row];
    const int t = threadIdx.x;
    const bool act = t < 192;
    const int d = t * 4;
    float v[4] = {};
    if (act) {
        const float4 w = *(const float4*)&we[(size_t)tok * D + d];
        const float4 p = *(const float4*)&pe[(size_t)s * D + d];
        const float4 tt = *(const float4*)&te[d];
        v[0] = w.x + p.x + tt.x; v[1] = w.y + p.y + tt.y;
        v[2] = w.z + p.z + tt.z; v[3] = w.w + p.w + tt.w;
    }
    const float mu = block_sum256(v[0] + v[1] + v[2] + v[3], sm) * (1.0f / D);
    float lvar = 0.f;
    if (act) {
#pragma unroll
        for (int i = 0; i < 4; ++i) { float dv = v[i] - mu; lvar += dv * dv; }
    }
    const float var = block_sum256(lvar, sm) * (1.0f / D);
    const float inv = rsqrtf(var + 1e-12f);
    if (act) {
        const float4 g4 = *(const float4*)&g[d];
        const float4 b4 = *(const float4*)&bb[d];
        float o[4];
        o[0] = (v[0] - mu) * inv * g4.x + b4.x;
        o[1] = (v[1] - mu) * inv * g4.y + b4.y;
        o[2] = (v[2] - mu) * inv * g4.z + b4.z;
        o[3] = (v[3] - mu) * inv * g4.w + b4.w;
        *(float4*)&hres[(size_t)row * D + d] = make_float4(o[0], o[1], o[2], o[3]);
        u16x4 ob;
#pragma unroll
        for (int i = 0; i < 4; ++i) ob[i] = f2h_u(o[i]);
        *(u16x4*)&hh[(size_t)row * D + d] = ob;
    }
}

// ---------------- (optional residual) + LayerNorm, fp32 -> fp32 stream + fp16 copy ----
template <bool HAS_RES>
__global__ __launch_bounds__(256) void add_ln_kernel(
    const float* __restrict__ inp, const float* __restrict__ res,
    const float* __restrict__ g, const float* __restrict__ bb,
    float* __restrict__ outres, unsigned short* __restrict__ outh) {
    __shared__ float sm[4];
    const int row = blockIdx.x;
    const int t = threadIdx.x;
    const bool act = t < 192;
    const int d = t * 4;
    float v[4] = {};
    if (act) {
        const float4 iv = *(const float4*)&inp[(size_t)row * D + d];
        v[0] = iv.x; v[1] = iv.y; v[2] = iv.z; v[3] = iv.w;
        if (HAS_RES) {
            const float4 rv = *(const float4*)&res[(size_t)row * D + d];
            v[0] += rv.x; v[1] += rv.y; v[2] += rv.z; v[3] += rv.w;
        }
    }
    const float mu = block_sum256(v[0] + v[1] + v[2] + v[3], sm) * (1.0f / D);
    float lvar = 0.f;
    if (act) {
#pragma unroll
        for (int i = 0; i < 4; ++i) { float dv = v[i] - mu; lvar += dv * dv; }
    }
    const float var = block_sum256(lvar, sm) * (1.0f / D);
    const float inv = rsqrtf(var + 1e-12f);
    if (act) {
        const float4 g4 = *(const float4*)&g[d];
        const float4 b4 = *(const float4*)&bb[d];
        float o[4];
        o[0] = (v[0] - mu) * inv * g4.x + b4.x;
        o[1] = (v[1] - mu) * inv * g4.y + b4.y;
        o[2] = (v[2] - mu) * inv * g4.z + b4.z;
        o[3] = (v[3] - mu) * inv * g4.w + b4.w;
        *(float4*)&outres[(size_t)row * D + d] = make_float4(o[0], o[1], o[2], o[3]);
        u16x4 ob;
#pragma unroll
        for (int i = 0; i < 4; ++i) ob[i] = f2h_u(o[i]);
        *(u16x4*)&outh[(size_t)row * D + d] = ob;
    }
}

// ======== shared fp16 MFMA GEMM body: 128x128 tile, BK=32, 4 waves ========
#define GEMM_BODY(A_, Bw_, K_)                                                       \
    constexpr int BK = 32;                                                           \
    __shared__ unsigned short Asl[2][128 * BK];                                      \
    __shared__ unsigned short Bsl[2][128 * BK];                                      \
    const int t = threadIdx.x;                                                       \
    const int lane = t & 63;                                                         \
    const int wid = t >> 6;                                                          \
    const int lr = lane & 15;                                                        \
    const int kh = lane >> 4;                                                        \
    const int wrBase = (wid >> 1) * 64;                                              \
    const int wcBase = (wid & 1) * 64;                                               \
    const int rowBase = blockIdx.y * 128;                                            \
    const int colBase = blockIdx.x * 128;                                            \
    f32x4 acc[4][4] = {};                                                            \
    const int r0 = t >> 2, c0 = (t & 3) ^ ((r0 >> 1) & 3);                           \
    const int s_hi = 256 + t;                                                        \
    const int r1 = s_hi >> 2, c1 = (s_hi & 3) ^ ((r1 >> 1) & 3);                     \
    const unsigned ldsOff0 = (unsigned)((t & 192) * 8);                              \
    const unsigned ldsOff1 = (unsigned)((256 + (t & 192)) * 8);                      \
    const int nt = (K_) / BK;                                                        \
    {                                                                                \
        gload16(A_ + (size_t)(rowBase + r0) * (K_) + c0 * 8, &Asl[0][ldsOff0]);      \
        gload16(A_ + (size_t)(rowBase + r1) * (K_) + c1 * 8, &Asl[0][ldsOff1]);      \
        gload16(Bw_ + (size_t)(colBase + r0) * (K_) + c0 * 8, &Bsl[0][ldsOff0]);     \
        gload16(Bw_ + (size_t)(colBase + r1) * (K_) + c1 * 8, &Bsl[0][ldsOff1]);     \
    }                                                                                \
    __syncthreads();                                                                 \
    for (int tt = 0; tt < nt; ++tt) {                                                \
        const int p = tt & 1;                                                        \
        if (tt + 1 < nt) {                                                           \
            const int k0 = (tt + 1) * BK;                                            \
            gload16(A_ + (size_t)(rowBase + r0) * (K_) + k0 + c0 * 8, &Asl[p^1][ldsOff0]); \
            gload16(A_ + (size_t)(rowBase + r1) * (K_) + k0 + c1 * 8, &Asl[p^1][ldsOff1]); \
            gload16(Bw_ + (size_t)(colBase + r0) * (K_) + k0 + c0 * 8, &Bsl[p^1][ldsOff0]);\
            gload16(Bw_ + (size_t)(colBase + r1) * (K_) + k0 + c1 * 8, &Bsl[p^1][ldsOff1]);\
        }                                                                            \
        f16x8 af[4], bfr[4];                                                         \
        _Pragma("unroll")                                                            \
        for (int mi = 0; mi < 4; ++mi) {                                             \
            const int ar = wrBase + mi * 16 + lr;                                    \
            const int ch = kh ^ ((ar >> 1) & 3);                                     \
            af[mi] = *(const f16x8*)&Asl[p][ar * BK + ch * 8];                       \
        }                                                                            \
        _Pragma("unroll")                                                            \
        for (int nj = 0; nj < 4; ++nj) {                                             \
            const int bc = wcBase + nj * 16 + lr;                                    \
            const int ch = kh ^ ((bc >> 1) & 3);                                     \
            bfr[nj] = *(const f16x8*)&Bsl[p][bc * BK + ch * 8];                      \
        }                                                                            \
        _Pragma("unroll")                                                            \
        for (int mi = 0; mi < 4; ++mi)                                               \
            _Pragma("unroll")                                                        \
            for (int nj = 0; nj < 4; ++nj)                                           \
                acc[mi][nj] = __builtin_amdgcn_mfma_f32_16x16x32_f16(                \
                    af[mi], bfr[nj], acc[mi][nj], 0, 0, 0);                          \
        __syncthreads();                                                             \
    }

// ---------------- generic GEMM: C[M,N] = A @ Bw^T + bias; CT=float|ushort(fp16) ----
template <int EPI, typename CT>
__global__ __launch_bounds__(256) void gemm_mfma_kernel(
    const unsigned short* __restrict__ A, const unsigned short* __restrict__ Bw,
    const float* __restrict__ bias, CT* __restrict__ C, int N, int K) {
    GEMM_BODY(A, Bw, K)
#pragma unroll
    for (int nj = 0; nj < 4; ++nj) {
        const int col = colBase + wcBase + nj * 16 + lr;
        const float bc = bias[col];
#pragma unroll
        for (int mi = 0; mi < 4; ++mi) {
            const int row = rowBase + wrBase + mi * 16 + kh * 4;
#pragma unroll
            for (int j = 0; j < 4; ++j) {
                float v = acc[mi][nj][j] + bc;
                if (EPI == 1) v = 0.5f * v * (1.0f + erff(v * 0.70710678118654752f));
                if constexpr (sizeof(CT) == 4) C[(size_t)(row + j) * N + col] = v;
                else                           C[(size_t)(row + j) * N + col] = f2h_u(v);
            }
        }
    }
}

// ---------------- QKV GEMM: q,k -> qkout [M][1536]; v -> vtout [BH][64][S] (V^T) ----
__global__ __launch_bounds__(256) void gemm_qkv_kernel(
    const unsigned short* __restrict__ A, const unsigned short* __restrict__ Bw,
    const float* __restrict__ bias, unsigned short* __restrict__ qkout,
    unsigned short* __restrict__ vtout) {
    GEMM_BODY(A, Bw, D)
    const bool isV = (colBase >= NQK);   // 128-aligned boundary -> block-uniform
#pragma unroll
    for (int nj = 0; nj < 4; ++nj) {
        const int col = colBase + wcBase + nj * 16 + lr;
        const float bc = bias[col];
        if (!isV) {
#pragma unroll
            for (int mi = 0; mi < 4; ++mi) {
                const int row = rowBase + wrBase + mi * 16 + kh * 4;
#pragma unroll
                for (int j = 0; j < 4; ++j)
                    qkout[(size_t)(row + j) * NQK + col] = f2h_u(acc[mi][nj][j] + bc);
            }
        } else {
            const int dd = col - NQK;
            const int h2 = dd >> 6, d6 = dd & 63;
#pragma unroll
            for (int mi = 0; mi < 4; ++mi) {
                const int row = rowBase + wrBase + mi * 16 + kh * 4;
                const int b2 = row >> 10, s2 = row & 1023;
                u16x4 ov;
#pragma unroll
                for (int j = 0; j < 4; ++j) ov[j] = f2h_u(acc[mi][nj][j] + bc);
                *(u16x4*)&vtout[(((size_t)(b2 * H + h2)) * 64 + d6) * S + s2] = ov;
            }
        }
    }
}

// ---------------- MFMA flash attention ----------------
// Block = (b, h, 64 q-rows), 4 waves; KV tiles of 64. All LDS tiles fp16,
// 16B chunks XOR-swizzled by (row&7); staged via pre-swizzled-global gload16.
__global__ __launch_bounds__(256) void attention_kernel(
    const unsigned short* __restrict__ qk,   // [M][1536] fp16 (q|k)
    const unsigned short* __restrict__ vt,   // [BH][64][S] fp16 (V^T per head)
    unsigned short* __restrict__ o) {        // [M][768] fp16
    __shared__ unsigned short Qs[64 * 64];
    __shared__ unsigned short Ks[64 * 64];
    __shared__ unsigned short Vt[64 * 64];
    __shared__ unsigned short Ps[4][16 * 64];

    const int t = threadIdx.x;
    const int qt = blockIdx.x;          // 0..15
    const int bh = blockIdx.y;          // 0..47
    const int b = bh / H, hh = bh % H;
    const int w = t >> 6;
    const int lr = t & 15;
    const int kh = (t >> 4) & 3;

    // staging geometry: slot s=t and s=256+t; row=s>>3, lds chunk=s&7,
    // global chunk g = (s&7) ^ (row&7)  (row+32 has same low bits)
    const int r0 = t >> 3;
    const int g0 = (t & 7) ^ (r0 & 7);
    const unsigned lo0 = (unsigned)((t & 192) * 8);
    const unsigned lo1 = (unsigned)(2048 + (t & 192) * 8);

    const size_t qrow0 = (size_t)(b * S + qt * 64);
    gload16(qk + (qrow0 + r0) * NQK + hh * HD + g0 * 8, &Qs[lo0]);
    gload16(qk + (qrow0 + r0 + 32) * NQK + hh * HD + g0 * 8, &Qs[lo1]);

    const unsigned short* kgb = qk + D + hh * HD;
    const unsigned short* vgb = vt + (size_t)bh * 64 * S;

    float m_[4] = {-INFINITY, -INFINITY, -INFINITY, -INFINITY};
    float l_[4] = {};
    f32x4 oacc[4] = {};
    const int swlo = (kh)     ^ (lr & 7);   // chunk idx, k-chunk 0
    const int swhi = (kh + 4) ^ (lr & 7);   // chunk idx, k-chunk 1

    for (int kt = 0; kt < S; kt += 64) {
        __syncthreads();   // prev tile fully consumed (also drains vmcnt)
        gload16(kgb + (size_t)(b * S + kt + r0) * NQK + g0 * 8, &Ks[lo0]);
        gload16(kgb + (size_t)(b * S + kt + r0 + 32) * NQK + g0 * 8, &Ks[lo1]);
        gload16(vgb + (size_t)r0 * S + kt + g0 * 8, &Vt[lo0]);
        gload16(vgb + (size_t)(r0 + 32) * S + kt + g0 * 8, &Vt[lo1]);
        __syncthreads();   // staged data visible

        // ---- QK^T: sc[nj][j] = scores rows kh*4+j, cols nj*16+lr ----
        const int qr = w * 16 + lr;
        f16x8 aq0 = *(const f16x8*)&Qs[qr * 64 + swlo * 8];
        f16x8 aq1 = *(const f16x8*)&Qs[qr * 64 + swhi * 8];
        f32x4 sc[4];
#pragma unroll
        for (int nj = 0; nj < 4; ++nj) {
            const int kr = nj * 16 + lr;
            f16x8 b0 = *(const f16x8*)&Ks[kr * 64 + swlo * 8];
            f16x8 b1 = *(const f16x8*)&Ks[kr * 64 + swhi * 8];
            f32x4 z = {};
            z = __builtin_amdgcn_mfma_f32_16x16x32_f16(aq0, b0, z, 0, 0, 0);
            z = __builtin_amdgcn_mfma_f32_16x16x32_f16(aq1, b1, z, 0, 0, 0);
            sc[nj] = z;
        }

        // ---- online softmax (scaled by 1/8) ----
        float alpha[4];
#pragma unroll
        for (int j = 0; j < 4; ++j) {
            float rm = fmaxf(fmaxf(sc[0][j], sc[1][j]), fmaxf(sc[2][j], sc[3][j])) * 0.125f;
#pragma unroll
            for (int off = 1; off < 16; off <<= 1) rm = fmaxf(rm, __shfl_xor(rm, off, 64));
            const float mn = fmaxf(m_[j], rm);
            alpha[j] = __expf(m_[j] - mn);
            m_[j] = mn;
        }
        float ph[4][4];
        float rs[4] = {};
#pragma unroll
        for (int nj = 0; nj < 4; ++nj)
#pragma unroll
            for (int j = 0; j < 4; ++j) {
                float p = __expf(fmaf(sc[nj][j], 0.125f, -m_[j]));
                ph[nj][j] = p;
                rs[j] += p;
            }
#pragma unroll
        for (int j = 0; j < 4; ++j) {
#pragma unroll
            for (int off = 1; off < 16; off <<= 1) rs[j] += __shfl_xor(rs[j], off, 64);
            l_[j] = l_[j] * alpha[j] + rs[j];
        }
        // write P strip (per-wave) fp16, swizzled
        unsigned short* psw = &Ps[w][0];
#pragma unroll
        for (int nj = 0; nj < 4; ++nj)
#pragma unroll
            for (int j = 0; j < 4; ++j) {
                const int pr = kh * 4 + j;
                const int pc = nj * 16 + lr;
                psw[pr * 64 + (((pc >> 3) ^ (pr & 7)) * 8) + (pc & 7)] = f2h_u(ph[nj][j]);
            }
#pragma unroll
        for (int nj = 0; nj < 4; ++nj)
#pragma unroll
            for (int j = 0; j < 4; ++j) oacc[nj][j] *= alpha[j];
        __syncthreads();   // P visible (conservative; P is wave-local)

        // ---- PV: oacc[nj] += P @ V ----
        f16x8 pa0 = *(const f16x8*)&psw[lr * 64 + swlo * 8];
        f16x8 pa1 = *(const f16x8*)&psw[lr * 64 + swhi * 8];
#pragma unroll
        for (int nj = 0; nj < 4; ++nj) {
            const int vr = nj * 16 + lr;
            f16x8 b0 = *(const f16x8*)&Vt[vr * 64 + swlo * 8];
            f16x8 b1 = *(const f16x8*)&Vt[vr * 64 + swhi * 8];
            oacc[nj] = __builtin_amdgcn_mfma_f32_16x16x32_f16(pa0, b0, oacc[nj], 0, 0, 0);
            oacc[nj] = __builtin_amdgcn_mfma_f32_16x16x32_f16(pa1, b1, oacc[nj], 0, 0, 0);
        }
    }

    float inv[4];
#pragma unroll
    for (int j = 0; j < 4; ++j) inv[j] = 1.0f / l_[j];
#pragma unroll
    for (int nj = 0; nj < 4; ++nj)
#pragma unroll
        for (int j = 0; j < 4; ++j) {
            const int token = b * S + qt * 64 + w * 16 + kh * 4 + j;
            o[(size_t)token * D + hh * HD + nj * 16 + lr] = f2h_u(oacc[nj][j] * inv[j]);
        }
}

// ---------------- pooler (fp32 stream) ----------------
__global__ __launch_bounds__(768) void pooler_kernel(
    const float* __restrict__ h, const float* __restrict__ Wp,
    const float* __restrict__ bp, float* __restrict__ out) {
    const int b = blockIdx.x;
    const int d = threadIdx.x;
    const float* hrow = h + (size_t)b * S * D;
    float acc = bp[d];
    for (int kk = 0; kk < D; ++kk) acc = fmaf(hrow[kk], Wp[(size_t)kk * D + d], acc);
    out[(size_t)b * D + d] = tanhf(acc);
}

}  // namespace

extern "C" void kernel_launch(void* const* d_in, const int* in_sizes, int n_in,
                              void* d_out, int out_size, void* d_ws, size_t ws_size,
                              hipStream_t stream) {
    (void)in_sizes; (void)n_in; (void)out_size; (void)ws_size;

    const int*   x     = (const int*)  d_in[0];
    const float* we    = (const float*)d_in[1];
    const float* pe    = (const float*)d_in[2];
    const float* te    = (const float*)d_in[3];
    const float* emb_g = (const float*)d_in[4];
    const float* emb_b = (const float*)d_in[5];
    const float* Wq    = (const float*)d_in[6];
    const float* bq    = (const float*)d_in[7];
    const float* Wk    = (const float*)d_in[8];
    const float* bk    = (const float*)d_in[9];
    const float* Wv    = (const float*)d_in[10];
    const float* bv    = (const float*)d_in[11];
    const float* Wo    = (const float*)d_in[12];
    const float* bo    = (const float*)d_in[13];
    const float* ln1_g = (const float*)d_in[14];
    const float* ln1_b = (const float*)d_in[15];
    const float* W1    = (const float*)d_in[16];
    const float* b1    = (const float*)d_in[17];
    const float* W2    = (const float*)d_in[18];
    const float* b2    = (const float*)d_in[19];
    const float* ln2_g = (const float*)d_in[20];
    const float* ln2_b = (const float*)d_in[21];
    const float* Wp    = (const float*)d_in[22];
    const float* bp    = (const float*)d_in[23];

    // workspace (~113 MB):
    //  h_res fp32 12.58 | h_f16 6.29 | blockA 25.17 (qk 12.58 + v_t 6.29 + attno 6.29,
    //  aliased by inter fp16 25.17) | oproj fp32 12.58 | fp16 weights 56.62 | bqkv
    char* wp8 = (char*)d_ws;
    float*          h_res  = (float*)wp8;              wp8 += (size_t)M * D * 4;
    unsigned short* h_f16  = (unsigned short*)wp8;     wp8 += (size_t)M * D * 2;
    unsigned short* blockA = (unsigned short*)wp8;     wp8 += (size_t)M * F * 2;
    unsigned short* qk_f   = blockA;                         // M*1536
    unsigned short* v_t    = blockA + (size_t)M * NQK;       // 48*64*1024
    unsigned short* attno  = v_t + (size_t)B * H * 64 * S;   // M*768
    unsigned short* inter  = blockA;                         // M*F (aliases all three)
    float*          oproj  = (float*)wp8;              wp8 += (size_t)M * D * 4;
    float*          ffn2o  = h_res;                          // FFN2 writes stream in place
    unsigned short* Wqkv_t = (unsigned short*)wp8;     wp8 += (size_t)L * NQKV * D * 2;
    unsigned short* Wo_t   = (unsigned short*)wp8;     wp8 += (size_t)L * D * D * 2;
    unsigned short* W1_t   = (unsigned short*)wp8;     wp8 += (size_t)L * F * D * 2;
    unsigned short* W2_t   = (unsigned short*)wp8;     wp8 += (size_t)L * D * F * 2;
    float*          bqkv   = (float*)wp8;

    transpose_qkvo_kernel<<<dim3(24, 24, 16), 256, 0, stream>>>(Wq, Wk, Wv, Wo, Wqkv_t, Wo_t);
    transpose_w_kernel<<<dim3(96, 24, 4), 256, 0, stream>>>(W1, W1_t, D, F);   // -> [F][D]
    transpose_w_kernel<<<dim3(24, 96, 4), 256, 0, stream>>>(W2, W2_t, F, D);   // -> [D][F]
    bias_concat_kernel<<<dim3((L * NQKV + 255) / 256), 256, 0, stream>>>(bq, bk, bv, bqkv);

    embed_ln_kernel<<<M, 256, 0, stream>>>(x, we, pe, te, emb_g, emb_b, h_res, h_f16);

    for (int l = 0; l < L; ++l) {
        gemm_qkv_kernel<<<dim3(NQKV / 128, M / 128), 256, 0, stream>>>(
            h_f16, Wqkv_t + (size_t)l * NQKV * D, bqkv + l * NQKV, qk_f, v_t);

        attention_kernel<<<dim3(S / 64, B * H), 256, 0, stream>>>(qk_f, v_t, attno);

        gemm_mfma_kernel<0, float><<<dim3(D / 128, M / 128), 256, 0, stream>>>(
            attno, Wo_t + (size_t)l * D * D, bo + l * D, oproj, D, D);
        add_ln_kernel<true><<<M, 256, 0, stream>>>(
            oproj, h_res, ln1_g + l * D, ln1_b + l * D, h_res, h_f16);

        gemm_mfma_kernel<1, unsigned short><<<dim3(F / 128, M / 128), 256, 0, stream>>>(
            h_f16, W1_t + (size_t)l * F * D, b1 + l * F, inter, F, D);
        gemm_mfma_kernel<1, float><<<dim3(D / 128, M / 128), 256, 0, stream>>>(
            inter, W2_t + (size_t)l * D * F, b2 + l * D, ffn2o, D, F);
        add_ln_kernel<false><<<M, 256, 0, stream>>>(
            ffn2o, nullptr, ln2_g + l * D, ln2_b + l * D, h_res, h_f16);
    }

    pooler_kernel<<<B, D, 0, stream>>>(h_res, Wp, bp, (float*)d_out);
}

// Round 6
// 897.526 us; speedup vs baseline: 18.9116x; 1.0627x over previous
//
#include <hip/hip_runtime.h>
#include <math.h>

namespace {

constexpr int B  = 4;
constexpr int S  = 1024;
constexpr int D  = 768;
constexpr int H  = 12;
constexpr int HD = 64;
constexpr int F  = 3072;
constexpr int L  = 4;
constexpr int M  = B * S;       // 4096 tokens
constexpr int NQKV = 3 * D;     // 2304
constexpr int NQK = 2 * D;      // 1536 (q|k packed)

typedef __attribute__((ext_vector_type(4))) float    f32x4;
typedef _Float16 f16x8 __attribute__((ext_vector_type(8)));
typedef __attribute__((ext_vector_type(8))) unsigned short u16x8;
typedef __attribute__((ext_vector_type(4))) unsigned short u16x4;

__device__ __forceinline__ unsigned short f2h_u(float f) {
    _Float16 h = (_Float16)f;
    return __builtin_bit_cast(unsigned short, h);
}

__device__ __forceinline__ void gload16(const void* gptr, void* ldsptr) {
    __builtin_amdgcn_global_load_lds(
        (const __attribute__((address_space(1))) unsigned int*)gptr,
        (__attribute__((address_space(3))) unsigned int*)ldsptr,
        16, 0, 0);
}

// ---------------- reductions ----------------
__device__ __forceinline__ float wave_sum(float v) {
#pragma unroll
    for (int off = 32; off; off >>= 1) v += __shfl_xor(v, off, 64);
    return v;
}
__device__ __forceinline__ float block_sum256(float v, float* sm) {
    v = wave_sum(v);
    __syncthreads();
    if ((threadIdx.x & 63) == 0) sm[threadIdx.x >> 6] = v;
    __syncthreads();
    return sm[0] + sm[1] + sm[2] + sm[3];
}

// ---------------- weight prep: transpose fp32 [R][C] -> fp16 [C][R] ----------------
__device__ __forceinline__ void transpose_tile(const float* __restrict__ src,
                                               unsigned short* __restrict__ dst,
                                               int R, int C) {
    __shared__ float tile[32][33];
    const int cb = blockIdx.x * 32, rb = blockIdx.y * 32;
    const int t = threadIdx.x;
    {
        const int r = t >> 3, cq = (t & 7) * 4;
        const float4 v = *(const float4*)&src[(size_t)(rb + r) * C + cb + cq];
        tile[r][cq + 0] = v.x; tile[r][cq + 1] = v.y;
        tile[r][cq + 2] = v.z; tile[r][cq + 3] = v.w;
    }
    __syncthreads();
    {
        const int dc = t >> 3, rq = (t & 7) * 4;
        u16x4 o;
#pragma unroll
        for (int j = 0; j < 4; ++j) o[j] = f2h_u(tile[rq + j][dc]);
        *(u16x4*)&dst[(size_t)(cb + dc) * R + rb + rq] = o;
    }
}

__global__ __launch_bounds__(256) void transpose_qkvo_kernel(
    const float* __restrict__ Wq, const float* __restrict__ Wk,
    const float* __restrict__ Wv, const float* __restrict__ Wo,
    unsigned short* __restrict__ Wqkv_t, unsigned short* __restrict__ Wo_t) {
    const int z = blockIdx.z;
    const int l = z >> 2, which = z & 3;
    const float* src = (which == 0 ? Wq : which == 1 ? Wk : which == 2 ? Wv : Wo)
                       + (size_t)l * D * D;
    unsigned short* dst = (which < 3)
        ? Wqkv_t + ((size_t)l * NQKV + which * D) * D
        : Wo_t + (size_t)l * D * D;
    transpose_tile(src, dst, D, D);
}

__global__ __launch_bounds__(256) void transpose_w_kernel(
    const float* __restrict__ src0, unsigned short* __restrict__ dst0, int R, int C) {
    const int l = blockIdx.z;
    transpose_tile(src0 + (size_t)l * R * C, dst0 + (size_t)l * R * C, R, C);
}

__global__ __launch_bounds__(256) void bias_concat_kernel(
    const float* __restrict__ bq, const float* __restrict__ bk,
    const float* __restrict__ bv, float* __restrict__ bqkv) {
    const int i = blockIdx.x * 256 + threadIdx.x;
    if (i >= L * NQKV) return;
    const int l = i / NQKV, j = i % NQKV;
    float v = (j < D) ? bq[l * D + j] : (j < 2 * D) ? bk[l * D + j - D] : bv[l * D + j - 2 * D];
    bqkv[i] = v;
}

// ---------------- embeddings + LayerNorm -> fp32 stream + fp16 copy ----------------
__global__ __launch_bounds__(256) void embed_ln_kernel(
    const int* __restrict__ x, const float* __restrict__ we,
    const float* __restrict__ pe, const float* __restrict__ te,
    const float* __restrict__ g, const float* __restrict__ bb,
    float* __restrict__ hres, unsigned short* __restrict__ hh) {
    __shared__ float sm[4];
    const int row = blockIdx.x;
    const int s = row & (S - 1);
    const int tok = x[row];
    const int t = threadIdx.x;
    const bool act = t < 192;
    const int d = t * 4;
    float v[4] = {};
    if (act) {
        const float4 w = *(const float4*)&we[(size_t)tok * D + d];
        const float4 p = *(const float4*)&pe[(size_t)s * D + d];
        const float4 tt = *(const float4*)&te[d];
        v[0] = w.x + p.x + tt.x; v[1] = w.y + p.y + tt.y;
        v[2] = w.z + p.z + tt.z; v[3] = w.w + p.w + tt.w;
    }
    const float mu = block_sum256(v[0] + v[1] + v[2] + v[3], sm) * (1.0f / D);
    float lvar = 0.f;
    if (act) {
#pragma unroll
        for (int i = 0; i < 4; ++i) { float dv = v[i] - mu; lvar += dv * dv; }
    }
    const float var = block_sum256(lvar, sm) * (1.0f / D);
    const float inv = rsqrtf(var + 1e-12f);
    if (act) {
        const float4 g4 = *(const float4*)&g[d];
        const float4 b4 = *(const float4*)&bb[d];
        float o[4];
        o[0] = (v[0] - mu) * inv * g4.x + b4.x;
        o[1] = (v[1] - mu) * inv * g4.y + b4.y;
        o[2] = (v[2] - mu) * inv * g4.z + b4.z;
        o[3] = (v[3] - mu) * inv * g4.w + b4.w;
        *(float4*)&hres[(size_t)row * D + d] = make_float4(o[0], o[1], o[2], o[3]);
        u16x4 ob;
#pragma unroll
        for (int i = 0; i < 4; ++i) ob[i] = f2h_u(o[i]);
        *(u16x4*)&hh[(size_t)row * D + d] = ob;
    }
}

// ---------------- (optional residual) + LayerNorm, fp32 -> fp32 stream + fp16 copy ----
template <bool HAS_RES>
__global__ __launch_bounds__(256) void add_ln_kernel(
    const float* __restrict__ inp, const float* __restrict__ res,
    const float* __restrict__ g, const float* __restrict__ bb,
    float* __restrict__ outres, unsigned short* __restrict__ outh) {
    __shared__ float sm[4];
    const int row = blockIdx.x;
    const int t = threadIdx.x;
    const bool act = t < 192;
    const int d = t * 4;
    float v[4] = {};
    if (act) {
        const float4 iv = *(const float4*)&inp[(size_t)row * D + d];
        v[0] = iv.x; v[1] = iv.y; v[2] = iv.z; v[3] = iv.w;
        if (HAS_RES) {
            const float4 rv = *(const float4*)&res[(size_t)row * D + d];
            v[0] += rv.x; v[1] += rv.y; v[2] += rv.z; v[3] += rv.w;
        }
    }
    const float mu = block_sum256(v[0] + v[1] + v[2] + v[3], sm) * (1.0f / D);
    float lvar = 0.f;
    if (act) {
#pragma unroll
        for (int i = 0; i < 4; ++i) { float dv = v[i] - mu; lvar += dv * dv; }
    }
    const float var = block_sum256(lvar, sm) * (1.0f / D);
    const float inv = rsqrtf(var + 1e-12f);
    if (act) {
        const float4 g4 = *(const float4*)&g[d];
        const float4 b4 = *(const float4*)&bb[d];
        float o[4];
        o[0] = (v[0] - mu) * inv * g4.x + b4.x;
        o[1] = (v[1] - mu) * inv * g4.y + b4.y;
        o[2] = (v[2] - mu) * inv * g4.z + b4.z;
        o[3] = (v[3] - mu) * inv * g4.w + b4.w;
        *(float4*)&outres[(size_t)row * D + d] = make_float4(o[0], o[1], o[2], o[3]);
        u16x4 ob;
#pragma unroll
        for (int i = 0; i < 4; ++i) ob[i] = f2h_u(o[i]);
        *(u16x4*)&outh[(size_t)row * D + d] = ob;
    }
}

// ======== shared fp16 MFMA GEMM body: 128x128 tile, BK=32, 4 waves ========
#define GEMM_BODY(A_, Bw_, K_)                                                       \
    constexpr int BK = 32;                                                           \
    __shared__ unsigned short Asl[2][128 * BK];                                      \
    __shared__ unsigned short Bsl[2][128 * BK];                                      \
    const int t = threadIdx.x;                                                       \
    const int lane = t & 63;                                                         \
    const int wid = t >> 6;                                                          \
    const int lr = lane & 15;                                                        \
    const int kh = lane >> 4;                                                        \
    const int wrBase = (wid >> 1) * 64;                                              \
    const int wcBase = (wid & 1) * 64;                                               \
    const int rowBase = blockIdx.y * 128;                                            \
    const int colBase = blockIdx.x * 128;                                            \
    f32x4 acc[4][4] = {};                                                            \
    const int r0 = t >> 2, c0 = (t & 3) ^ ((r0 >> 1) & 3);                           \
    const int s_hi = 256 + t;                                                        \
    const int r1 = s_hi >> 2, c1 = (s_hi & 3) ^ ((r1 >> 1) & 3);                     \
    const unsigned ldsOff0 = (unsigned)((t & 192) * 8);                              \
    const unsigned ldsOff1 = (unsigned)((256 + (t & 192)) * 8);                      \
    const int nt = (K_) / BK;                                                        \
    {                                                                                \
        gload16(A_ + (size_t)(rowBase + r0) * (K_) + c0 * 8, &Asl[0][ldsOff0]);      \
        gload16(A_ + (size_t)(rowBase + r1) * (K_) + c1 * 8, &Asl[0][ldsOff1]);      \
        gload16(Bw_ + (size_t)(colBase + r0) * (K_) + c0 * 8, &Bsl[0][ldsOff0]);     \
        gload16(Bw_ + (size_t)(colBase + r1) * (K_) + c1 * 8, &Bsl[0][ldsOff1]);     \
    }                                                                                \
    __syncthreads();                                                                 \
    for (int tt = 0; tt < nt; ++tt) {                                                \
        const int p = tt & 1;                                                        \
        if (tt + 1 < nt) {                                                           \
            const int k0 = (tt + 1) * BK;                                            \
            gload16(A_ + (size_t)(rowBase + r0) * (K_) + k0 + c0 * 8, &Asl[p^1][ldsOff0]); \
            gload16(A_ + (size_t)(rowBase + r1) * (K_) + k0 + c1 * 8, &Asl[p^1][ldsOff1]); \
            gload16(Bw_ + (size_t)(colBase + r0) * (K_) + k0 + c0 * 8, &Bsl[p^1][ldsOff0]);\
            gload16(Bw_ + (size_t)(colBase + r1) * (K_) + k0 + c1 * 8, &Bsl[p^1][ldsOff1]);\
        }                                                                            \
        f16x8 af[4], bfr[4];                                                         \
        _Pragma("unroll")                                                            \
        for (int mi = 0; mi < 4; ++mi) {                                             \
            const int ar = wrBase + mi * 16 + lr;                                    \
            const int ch = kh ^ ((ar >> 1) & 3);                                     \
            af[mi] = *(const f16x8*)&Asl[p][ar * BK + ch * 8];                       \
        }                                                                            \
        _Pragma("unroll")                                                            \
        for (int nj = 0; nj < 4; ++nj) {                                             \
            const int bc = wcBase + nj * 16 + lr;                                    \
            const int ch = kh ^ ((bc >> 1) & 3);                                     \
            bfr[nj] = *(const f16x8*)&Bsl[p][bc * BK + ch * 8];                      \
        }                                                                            \
        _Pragma("unroll")                                                            \
        for (int mi = 0; mi < 4; ++mi)                                               \
            _Pragma("unroll")                                                        \
            for (int nj = 0; nj < 4; ++nj)                                           \
                acc[mi][nj] = __builtin_amdgcn_mfma_f32_16x16x32_f16(                \
                    af[mi], bfr[nj], acc[mi][nj], 0, 0, 0);                          \
        __syncthreads();                                                             \
    }

// ---------------- generic GEMM: C[M,N] = A @ Bw^T + bias; CT=float|ushort(fp16) ----
template <int EPI, typename CT>
__global__ __launch_bounds__(256) void gemm_mfma_kernel(
    const unsigned short* __restrict__ A, const unsigned short* __restrict__ Bw,
    const float* __restrict__ bias, CT* __restrict__ C, int N, int K) {
    GEMM_BODY(A, Bw, K)
#pragma unroll
    for (int nj = 0; nj < 4; ++nj) {
        const int col = colBase + wcBase + nj * 16 + lr;
        const float bc = bias[col];
#pragma unroll
        for (int mi = 0; mi < 4; ++mi) {
            const int row = rowBase + wrBase + mi * 16 + kh * 4;
#pragma unroll
            for (int j = 0; j < 4; ++j) {
                float v = acc[mi][nj][j] + bc;
                if (EPI == 1) v = 0.5f * v * (1.0f + erff(v * 0.70710678118654752f));
                if constexpr (sizeof(CT) == 4) C[(size_t)(row + j) * N + col] = v;
                else                           C[(size_t)(row + j) * N + col] = f2h_u(v);
            }
        }
    }
}

// ---------------- QKV GEMM: q,k -> qkout [M][1536]; v -> vtout [BH][64][S] (V^T) ----
__global__ __launch_bounds__(256) void gemm_qkv_kernel(
    const unsigned short* __restrict__ A, const unsigned short* __restrict__ Bw,
    const float* __restrict__ bias, unsigned short* __restrict__ qkout,
    unsigned short* __restrict__ vtout) {
    GEMM_BODY(A, Bw, D)
    const bool isV = (colBase >= NQK);   // 128-aligned boundary -> block-uniform
#pragma unroll
    for (int nj = 0; nj < 4; ++nj) {
        const int col = colBase + wcBase + nj * 16 + lr;
        const float bc = bias[col];
        if (!isV) {
#pragma unroll
            for (int mi = 0; mi < 4; ++mi) {
                const int row = rowBase + wrBase + mi * 16 + kh * 4;
#pragma unroll
                for (int j = 0; j < 4; ++j)
                    qkout[(size_t)(row + j) * NQK + col] = f2h_u(acc[mi][nj][j] + bc);
            }
        } else {
            const int dd = col - NQK;
            const int h2 = dd >> 6, d6 = dd & 63;
#pragma unroll
            for (int mi = 0; mi < 4; ++mi) {
                const int row = rowBase + wrBase + mi * 16 + kh * 4;
                const int b2 = row >> 10, s2 = row & 1023;
                u16x4 ov;
#pragma unroll
                for (int j = 0; j < 4; ++j) ov[j] = f2h_u(acc[mi][nj][j] + bc);
                *(u16x4*)&vtout[(((size_t)(b2 * H + h2)) * 64 + d6) * S + s2] = ov;
            }
        }
    }
}

// ---------------- MFMA flash attention (double-buffered, 1 barrier/tile) ----------------
// Block = (b, h, 64 q-rows), 4 waves; KV tiles of 64. LDS tiles fp16,
// 16B chunks XOR-swizzled by (row&7); staged via pre-swizzled-global gload16.
// Next tile's loads issued BEFORE current tile's compute (latency hidden);
// single __syncthreads (drains vmcnt) per tile. P strip is wave-local: no barrier.
__global__ __launch_bounds__(256) void attention_kernel(
    const unsigned short* __restrict__ qk,   // [M][1536] fp16 (q|k)
    const unsigned short* __restrict__ vt,   // [BH][64][S] fp16 (V^T per head)
    unsigned short* __restrict__ o) {        // [M][768] fp16
    __shared__ unsigned short Qs[64 * 64];
    __shared__ unsigned short Ks[2][64 * 64];
    __shared__ unsigned short Vt[2][64 * 64];
    __shared__ _Float16 Ps[4][16 * 64];

    const int t = threadIdx.x;
    const int qt = blockIdx.x;          // 0..15
    const int bh = blockIdx.y;          // 0..47
    const int b = bh / H, hh = bh % H;
    const int w = t >> 6;
    const int lr = t & 15;
    const int kh = (t >> 4) & 3;

    // staging geometry: slot s=t and s=256+t; row=s>>3, lds chunk=s&7,
    // global chunk g = (s&7) ^ (row&7)  (row+32 has same low bits)
    const int r0 = t >> 3;
    const int g0 = (t & 7) ^ (r0 & 7);
    const unsigned lo0 = (unsigned)((t & 192) * 8);
    const unsigned lo1 = (unsigned)(2048 + (t & 192) * 8);

    const unsigned short* kgb = qk + D + hh * HD;
    const unsigned short* vgb = vt + (size_t)bh * 64 * S;

    // prologue: Q + first K/V tile
    {
        const size_t qrow0 = (size_t)(b * S + qt * 64);
        gload16(qk + (qrow0 + r0) * NQK + hh * HD + g0 * 8, &Qs[lo0]);
        gload16(qk + (qrow0 + r0 + 32) * NQK + hh * HD + g0 * 8, &Qs[lo1]);
        gload16(kgb + (size_t)(b * S + r0) * NQK + g0 * 8, &Ks[0][lo0]);
        gload16(kgb + (size_t)(b * S + r0 + 32) * NQK + g0 * 8, &Ks[0][lo1]);
        gload16(vgb + (size_t)r0 * S + g0 * 8, &Vt[0][lo0]);
        gload16(vgb + (size_t)(r0 + 32) * S + g0 * 8, &Vt[0][lo1]);
    }
    __syncthreads();

    float m_[4] = {-INFINITY, -INFINITY, -INFINITY, -INFINITY};
    float l_[4] = {};
    f32x4 oacc[4] = {};
    const int swlo = (kh)     ^ (lr & 7);   // chunk idx, k-chunk 0
    const int swhi = (kh + 4) ^ (lr & 7);   // chunk idx, k-chunk 1
    constexpr int NT = S / 64;

    for (int it = 0; it < NT; ++it) {
        const int cur = it & 1;
        if (it + 1 < NT) {   // issue next tile now; completes by end-of-iter barrier
            const int kt = (it + 1) * 64;
            gload16(kgb + (size_t)(b * S + kt + r0) * NQK + g0 * 8, &Ks[cur ^ 1][lo0]);
            gload16(kgb + (size_t)(b * S + kt + r0 + 32) * NQK + g0 * 8, &Ks[cur ^ 1][lo1]);
            gload16(vgb + (size_t)r0 * S + kt + g0 * 8, &Vt[cur ^ 1][lo0]);
            gload16(vgb + (size_t)(r0 + 32) * S + kt + g0 * 8, &Vt[cur ^ 1][lo1]);
        }

        // ---- QK^T: sc[nj][j] = scores rows kh*4+j, cols nj*16+lr ----
        const int qr = w * 16 + lr;
        f16x8 aq0 = *(const f16x8*)&Qs[qr * 64 + swlo * 8];
        f16x8 aq1 = *(const f16x8*)&Qs[qr * 64 + swhi * 8];
        f32x4 sc[4];
        __builtin_amdgcn_s_setprio(1);
#pragma unroll
        for (int nj = 0; nj < 4; ++nj) {
            const int kr = nj * 16 + lr;
            f16x8 b0 = *(const f16x8*)&Ks[cur][kr * 64 + swlo * 8];
            f16x8 b1 = *(const f16x8*)&Ks[cur][kr * 64 + swhi * 8];
            f32x4 z = {};
            z = __builtin_amdgcn_mfma_f32_16x16x32_f16(aq0, b0, z, 0, 0, 0);
            z = __builtin_amdgcn_mfma_f32_16x16x32_f16(aq1, b1, z, 0, 0, 0);
            sc[nj] = z;
        }
        __builtin_amdgcn_s_setprio(0);

        // ---- online softmax (scaled by 1/8) ----
        float alpha[4];
#pragma unroll
        for (int j = 0; j < 4; ++j) {
            float rm = fmaxf(fmaxf(sc[0][j], sc[1][j]), fmaxf(sc[2][j], sc[3][j])) * 0.125f;
#pragma unroll
            for (int off = 1; off < 16; off <<= 1) rm = fmaxf(rm, __shfl_xor(rm, off, 64));
            const float mn = fmaxf(m_[j], rm);
            alpha[j] = __expf(m_[j] - mn);
            m_[j] = mn;
        }
        float ph[4][4];
        float rs[4] = {};
#pragma unroll
        for (int nj = 0; nj < 4; ++nj)
#pragma unroll
            for (int j = 0; j < 4; ++j) {
                float p = __expf(fmaf(sc[nj][j], 0.125f, -m_[j]));
                ph[nj][j] = p;
                rs[j] += p;
            }
#pragma unroll
        for (int j = 0; j < 4; ++j) {
#pragma unroll
            for (int off = 1; off < 16; off <<= 1) rs[j] += __shfl_xor(rs[j], off, 64);
            l_[j] = l_[j] * alpha[j] + rs[j];
        }
        // write P strip (wave-local, no barrier needed)
        _Float16* psw = &Ps[w][0];
#pragma unroll
        for (int nj = 0; nj < 4; ++nj)
#pragma unroll
            for (int j = 0; j < 4; ++j) {
                const int pr = kh * 4 + j;
                const int pc = nj * 16 + lr;
                psw[pr * 64 + (((pc >> 3) ^ (pr & 7)) * 8) + (pc & 7)] = (_Float16)ph[nj][j];
            }
#pragma unroll
        for (int nj = 0; nj < 4; ++nj)
#pragma unroll
            for (int j = 0; j < 4; ++j) oacc[nj][j] *= alpha[j];

        // ---- PV: oacc[nj] += P @ V ----
        f16x8 pa0 = *(const f16x8*)&psw[lr * 64 + swlo * 8];
        f16x8 pa1 = *(const f16x8*)&psw[lr * 64 + swhi * 8];
        __builtin_amdgcn_s_setprio(1);
#pragma unroll
        for (int nj = 0; nj < 4; ++nj) {
            const int vr = nj * 16 + lr;
            f16x8 b0 = *(const f16x8*)&Vt[cur][vr * 64 + swlo * 8];
            f16x8 b1 = *(const f16x8*)&Vt[cur][vr * 64 + swhi * 8];
            oacc[nj] = __builtin_amdgcn_mfma_f32_16x16x32_f16(pa0, b0, oacc[nj], 0, 0, 0);
            oacc[nj] = __builtin_amdgcn_mfma_f32_16x16x32_f16(pa1, b1, oacc[nj], 0, 0, 0);
        }
        __builtin_amdgcn_s_setprio(0);

        __syncthreads();   // drains vmcnt(0): next tile staged; cur free for overwrite
    }

    float inv[4];
#pragma unroll
    for (int j = 0; j < 4; ++j) inv[j] = 1.0f / l_[j];
#pragma unroll
    for (int nj = 0; nj < 4; ++nj)
#pragma unroll
        for (int j = 0; j < 4; ++j) {
            const int token = b * S + qt * 64 + w * 16 + kh * 4 + j;
            o[(size_t)token * D + hh * HD + nj * 16 + lr] = f2h_u(oacc[nj][j] * inv[j]);
        }
}

// ---------------- pooler: split-K partial + reduce ----------------
// partial[b][slice][d] = sum_{k in slice of 48} h[b,0,k] * Wp[k,d]
__global__ __launch_bounds__(768) void pooler_partial_kernel(
    const float* __restrict__ h, const float* __restrict__ Wp,
    float* __restrict__ partial) {
    const int slice = blockIdx.x;     // 0..15
    const int b = blockIdx.y;         // 0..3
    const int d = threadIdx.x;        // 0..767
    const float* hrow = h + (size_t)b * S * D + slice * 48;
    const float* wcol = Wp + (size_t)slice * 48 * D + d;
    float acc = 0.f;
#pragma unroll
    for (int kk = 0; kk < 48; ++kk) acc = fmaf(hrow[kk], wcol[(size_t)kk * D], acc);
    partial[((size_t)b * 16 + slice) * D + d] = acc;
}

__global__ __launch_bounds__(768) void pooler_reduce_kernel(
    const float* __restrict__ partial, const float* __restrict__ bp,
    float* __restrict__ out) {
    const int b = blockIdx.x;
    const int d = threadIdx.x;
    float acc = bp[d];
#pragma unroll
    for (int s2 = 0; s2 < 16; ++s2) acc += partial[((size_t)b * 16 + s2) * D + d];
    out[(size_t)b * D + d] = tanhf(acc);
}

}  // namespace

extern "C" void kernel_launch(void* const* d_in, const int* in_sizes, int n_in,
                              void* d_out, int out_size, void* d_ws, size_t ws_size,
                              hipStream_t stream) {
    (void)in_sizes; (void)n_in; (void)out_size; (void)ws_size;

    const int*   x     = (const int*)  d_in[0];
    const float* we    = (const float*)d_in[1];
    const float* pe    = (const float*)d_in[2];
    const float* te    = (const float*)d_in[3];
    const float* emb_g = (const float*)d_in[4];
    const float* emb_b = (const float*)d_in[5];
    const float* Wq    = (const float*)d_in[6];
    const float* bq    = (const float*)d_in[7];
    const float* Wk    = (const float*)d_in[8];
    const float* bk    = (const float*)d_in[9];
    const float* Wv    = (const float*)d_in[10];
    const float* bv    = (const float*)d_in[11];
    const float* Wo    = (const float*)d_in[12];
    const float* bo    = (const float*)d_in[13];
    const float* ln1_g = (const float*)d_in[14];
    const float* ln1_b = (const float*)d_in[15];
    const float* W1    = (const float*)d_in[16];
    const float* b1    = (const float*)d_in[17];
    const float* W2    = (const float*)d_in[18];
    const float* b2    = (const float*)d_in[19];
    const float* ln2_g = (const float*)d_in[20];
    const float* ln2_b = (const float*)d_in[21];
    const float* Wp    = (const float*)d_in[22];
    const float* bp    = (const float*)d_in[23];

    // workspace (~113.5 MB)
    char* wp8 = (char*)d_ws;
    float*          h_res  = (float*)wp8;              wp8 += (size_t)M * D * 4;
    unsigned short* h_f16  = (unsigned short*)wp8;     wp8 += (size_t)M * D * 2;
    unsigned short* blockA = (unsigned short*)wp8;     wp8 += (size_t)M * F * 2;
    unsigned short* qk_f   = blockA;                         // M*1536
    unsigned short* v_t    = blockA + (size_t)M * NQK;       // 48*64*1024
    unsigned short* attno  = v_t + (size_t)B * H * 64 * S;   // M*768
    unsigned short* inter  = blockA;                         // M*F (aliases all three)
    float*          oproj  = (float*)wp8;              wp8 += (size_t)M * D * 4;
    float*          ffn2o  = h_res;                          // FFN2 writes stream in place
    unsigned short* Wqkv_t = (unsigned short*)wp8;     wp8 += (size_t)L * NQKV * D * 2;
    unsigned short* Wo_t   = (unsigned short*)wp8;     wp8 += (size_t)L * D * D * 2;
    unsigned short* W1_t   = (unsigned short*)wp8;     wp8 += (size_t)L * F * D * 2;
    unsigned short* W2_t   = (unsigned short*)wp8;     wp8 += (size_t)L * D * F * 2;
    float*          bqkv   = (float*)wp8;              wp8 += (size_t)L * NQKV * 4;
    float*          ppart  = (float*)wp8;                    // 4*16*768 fp32

    transpose_qkvo_kernel<<<dim3(24, 24, 16), 256, 0, stream>>>(Wq, Wk, Wv, Wo, Wqkv_t, Wo_t);
    transpose_w_kernel<<<dim3(96, 24, 4), 256, 0, stream>>>(W1, W1_t, D, F);   // -> [F][D]
    transpose_w_kernel<<<dim3(24, 96, 4), 256, 0, stream>>>(W2, W2_t, F, D);   // -> [D][F]
    bias_concat_kernel<<<dim3((L * NQKV + 255) / 256), 256, 0, stream>>>(bq, bk, bv, bqkv);

    embed_ln_kernel<<<M, 256, 0, stream>>>(x, we, pe, te, emb_g, emb_b, h_res, h_f16);

    for (int l = 0; l < L; ++l) {
        gemm_qkv_kernel<<<dim3(NQKV / 128, M / 128), 256, 0, stream>>>(
            h_f16, Wqkv_t + (size_t)l * NQKV * D, bqkv + l * NQKV, qk_f, v_t);

        attention_kernel<<<dim3(S / 64, B * H), 256, 0, stream>>>(qk_f, v_t, attno);

        gemm_mfma_kernel<0, float><<<dim3(D / 128, M / 128), 256, 0, stream>>>(
            attno, Wo_t + (size_t)l * D * D, bo + l * D, oproj, D, D);
        add_ln_kernel<true><<<M, 256, 0, stream>>>(
            oproj, h_res, ln1_g + l * D, ln1_b + l * D, h_res, h_f16);

        gemm_mfma_kernel<1, unsigned short><<<dim3(F / 128, M / 128), 256, 0, stream>>>(
            h_f16, W1_t + (size_t)l * F * D, b1 + l * F, inter, F, D);
        gemm_mfma_kernel<1, float><<<dim3(D / 128, M / 128), 256, 0, stream>>>(
            inter, W2_t + (size_t)l * D * F, b2 + l * D, ffn2o, D, F);
        add_ln_kernel<false><<<M, 256, 0, stream>>>(
            ffn2o, nullptr, ln2_g + l * D, ln2_b + l * D, h_res, h_f16);
    }

    pooler_partial_kernel<<<dim3(16, B), 768, 0, stream>>>(h_res, Wp, ppart);
    pooler_reduce_kernel<<<B, 768, 0, stream>>>(ppart, bp, (float*)d_out);
}